// Round 8
// baseline (46245.639 us; speedup 1.0000x reference)
//
#include <hip/hip_runtime.h>
#include <hip/hip_bf16.h>

#define BB    256
#define NCH   23
#define TT    19
#define SS    437          // NCH*TT
#define BSR   111872       // BB*SS
#define EMBD  256
#define NHEAD 8
#define DH    32
#define NFREQ 101
#define NFFT  200
#define HOPSZ 100
#define TSLEN 2000
#define HID   1024
#define NDEPTH 4
#define NTOK  28639232     // BSR*EMBD

__device__ __forceinline__ float gelu_f(float x){
    return 0.5f*x*(1.0f + tanhf(0.7978845608028654f*(x + 0.044715f*x*x*x)));
}

// ---------------- fused spectrogram: one block per (b,c,t) frame ----------------
__global__ __launch_bounds__(256) void spec_kernel(const float* __restrict__ x,
                                                   float* __restrict__ spec)
{
    __shared__ float fr[NFFT];
    long row = blockIdx.x;              // row = (b*NCH+c)*TT + t
    int  t   = (int)(row % TT);
    long bc  = row / TT;
    int tid = threadIdx.x;
    if(tid < NFFT) fr[tid] = x[bc*(long)TSLEN + (long)t*HOPSZ + tid];
    __syncthreads();
    if(tid < NFREQ){
        float cs = 0.f, sn = 0.f;
        for(int n = 0; n < NFFT; ++n){
            int ph = (n * tid) % NFFT;                 // exact phase reduction
            float ang = 6.283185307179586f * (float)ph * (1.0f/(float)NFFT);
            float s, c;
            sincosf(ang, &s, &c);
            float xv = fr[n];
            cs = fmaf(xv, c, cs);
            sn = fmaf(xv, s, sn);
        }
        spec[row*NFREQ + tid] = sqrtf(cs*cs + sn*sn);
    }
}

// ---------------- fused emb projection + epilogue + mask outputs (all f32) -----
__global__ __launch_bounds__(256) void emb_kernel(const float* __restrict__ spec,
    const float* __restrict__ Wp, const float* __restrict__ bp,
    const float* __restrict__ ctok, const float* __restrict__ noise,
    float* __restrict__ bufH, float* __restrict__ o_emb,
    float* __restrict__ o_masked, float* __restrict__ o_mask)
{
    __shared__ float sp[NFREQ];
    long row = blockIdx.x;
    int  t   = (int)(row % TT);
    long rg  = row / TT;
    int  c   = (int)(rg % NCH);
    int  e   = threadIdx.x;
    if(e < NFREQ) sp[e] = spec[row*NFREQ + e];
    __syncthreads();
    // posenc inline: even e=2j -> sin(t*div_j), odd -> cos(t*div_j)
    int j = e >> 1;
    float div = expf((float)(2*j) * (-9.210340371976184f/256.0f)); // -ln(10000)/256
    float ang = (float)t * div;
    float acc = bp[e] + ctok[c*EMBD + e] + ((e & 1) ? cosf(ang) : sinf(ang));
    for(int k = 0; k < NFREQ; ++k)
        acc = fmaf(sp[k], Wp[k*EMBD + e], acc);
    long i = row*EMBD + e;
    o_emb[i] = acc;
    float mn = noise[i];
    bool  m  = mn < 0.9f;
    float md = m ? 0.0f : acc;
    bufH[i]     = md;
    o_masked[i] = md;
    o_mask[i]   = m ? 1.0f : 0.0f;
}

// ---------------- textbook 16x16 tiled SGEMM ----------------
// MODE 0: C = A@B ; MODE 1: C += A@B + bias ; MODE 2: C = gelu(A@B + bias)
template<int MODE>
__global__ __launch_bounds__(256) void sgemm(
    const float* __restrict__ A, const float* __restrict__ Bm,
    const float* __restrict__ bias, float* __restrict__ C,
    int M, int N, int K, int lda, int ldb, int ldc)
{
    __shared__ float As[16][17];
    __shared__ float Bs[16][17];
    int tx = threadIdx.x, ty = threadIdx.y;
    int m = blockIdx.y*16 + ty;
    int n = blockIdx.x*16 + tx;
    float acc = 0.f;
    for(int k0 = 0; k0 < K; k0 += 16){
        As[ty][tx] = A[(long)m*lda + k0 + tx];
        Bs[ty][tx] = Bm[(long)(k0+ty)*ldb + n];
        __syncthreads();
        #pragma unroll
        for(int kk = 0; kk < 16; ++kk)
            acc = fmaf(As[ty][kk], Bs[kk][tx], acc);
        __syncthreads();
    }
    float* cp = C + (long)m*ldc + n;
    if(MODE == 0){
        *cp = acc;
    } else if(MODE == 1){
        *cp = *cp + acc + bias[n];
    } else {
        *cp = gelu_f(acc + bias[n]);
    }
}

// ---------------- layernorm (wave per row) ----------------
__global__ __launch_bounds__(256) void ln_kernel(const float* __restrict__ X,
    const float* __restrict__ s, const float* __restrict__ b, float* __restrict__ Y)
{
    int w = threadIdx.x >> 6, lane = threadIdx.x & 63;
    long row = (long)blockIdx.x*4 + w;
    const float* xr = X + row*EMBD;
    float4 v = *(const float4*)(xr + lane*4);
    float sum = v.x + v.y + v.z + v.w;
    #pragma unroll
    for(int o=32;o>0;o>>=1) sum += __shfl_xor(sum, o, 64);
    float mu = sum * (1.0f/256.0f);
    float dx = v.x-mu, dy = v.y-mu, dz = v.z-mu, dw = v.w-mu;
    float vs = dx*dx + dy*dy + dz*dz + dw*dw;
    #pragma unroll
    for(int o=32;o>0;o>>=1) vs += __shfl_xor(vs, o, 64);
    float rstd = rsqrtf(vs*(1.0f/256.0f) + 1e-5f);
    float4 s4 = *(const float4*)(s + lane*4);
    float4 b4 = *(const float4*)(b + lane*4);
    float4 o4;
    o4.x = dx*rstd*s4.x + b4.x;
    o4.y = dy*rstd*s4.y + b4.y;
    o4.z = dz*rstd*s4.z + b4.z;
    o4.w = dw*rstd*s4.w + b4.w;
    *(float4*)(Y + row*EMBD + lane*4) = o4;
}

// ---------------- k-softmax column stats over S ----------------
__global__ void colstats(const float* __restrict__ klog, float* __restrict__ kmax,
                         float* __restrict__ ksum)
{
    int b = blockIdx.x, c = threadIdx.x;
    const float* p = klog + (long)b*SS*EMBD + c;
    float m = -1e30f, sacc = 0.f;
    for(int n=0;n<SS;++n){
        float x = p[(long)n*EMBD];
        if(x > m){ sacc = sacc*expf(m-x) + 1.0f; m = x; }
        else     { sacc += expf(x-m); }
    }
    kmax[b*EMBD+c] = m;
    ksum[b*EMBD+c] = sacc;
}

// ---------------- ctx[b,h,d,e] = sum_n softmax_S(k)[n,d] * v[n,e] ----------------
__global__ __launch_bounds__(256) void ctx_kernel(const float* __restrict__ klog,
    const float* __restrict__ v, const float* __restrict__ kmax,
    const float* __restrict__ ksum, float* __restrict__ ctx)
{
    __shared__ float kt[16][DH], vt[16][DH];
    int bh = blockIdx.x; int b = bh >> 3, h = bh & 7;
    int tid = threadIdx.x;
    int d = tid >> 3, e4 = (tid & 7) * 4;
    float km = kmax[b*EMBD + h*DH + d];
    float a0=0,a1=0,a2=0,a3=0;
    for(int n0=0;n0<SS;n0+=16){
        __syncthreads();
        #pragma unroll
        for(int i=0;i<2;++i){
            int e = tid + i*256;
            int nn = e >> 5, dd = e & 31;
            int n = n0 + nn;
            float kv, vv;
            if(n < SS){
                long off = ((long)(b*SS+n))*EMBD + h*DH + dd;
                kv = klog[off];
                vv = v[off];
            } else { kv = -1e30f; vv = 0.f; }
            kt[nn][dd] = kv; vt[nn][dd] = vv;
        }
        __syncthreads();
        #pragma unroll
        for(int nn=0;nn<16;++nn){
            float ke = expf(kt[nn][d] - km);
            a0 = fmaf(ke, vt[nn][e4+0], a0);
            a1 = fmaf(ke, vt[nn][e4+1], a1);
            a2 = fmaf(ke, vt[nn][e4+2], a2);
            a3 = fmaf(ke, vt[nn][e4+3], a3);
        }
    }
    float inv = 1.0f / ksum[b*EMBD + h*DH + d];
    float* op = ctx + ((long)bh*DH + d)*DH + e4;
    op[0]=a0*inv; op[1]=a1*inv; op[2]=a2*inv; op[3]=a3*inv;
}

// ---------------- per-token q-softmax + att = q @ ctx ----------------
__global__ __launch_bounds__(256) void att_kernel(const float* __restrict__ qlog,
    const float* __restrict__ ctx, float* __restrict__ att)
{
    __shared__ float qs[4][EMBD];
    int w = threadIdx.x >> 6, lane = threadIdx.x & 63;
    int b = blockIdx.y;
    int s = blockIdx.x*4 + w;
    if(s >= SS) return;
    long row = (long)b*SS + s;
    float4 q4 = *(const float4*)(qlog + row*EMBD + lane*4);
    float m = fmaxf(fmaxf(q4.x,q4.y), fmaxf(q4.z,q4.w));
    #pragma unroll
    for(int o=1;o<8;o<<=1) m = fmaxf(m, __shfl_xor(m, o, 64));
    float e0 = expf(q4.x-m), e1 = expf(q4.y-m), e2 = expf(q4.z-m), e3 = expf(q4.w-m);
    float ssum = e0+e1+e2+e3;
    #pragma unroll
    for(int o=1;o<8;o<<=1) ssum += __shfl_xor(ssum, o, 64);
    float sc = 0.17677669529663687f / ssum;  // DHEAD^-0.5 / sum
    *(float4*)&qs[w][lane*4] = make_float4(e0*sc, e1*sc, e2*sc, e3*sc);
    int head = lane >> 3;
    int ecol = (lane & 7) * 4;
    const float* cb = ctx + ((long)(b*NHEAD + head))*DH*DH + ecol;
    float a0=0,a1=0,a2=0,a3=0;
    #pragma unroll
    for(int d=0; d<DH; ++d){
        float qd = qs[w][head*DH + d];
        float4 c4 = *(const float4*)(cb + d*DH);
        a0 = fmaf(qd, c4.x, a0);
        a1 = fmaf(qd, c4.y, a1);
        a2 = fmaf(qd, c4.z, a2);
        a3 = fmaf(qd, c4.w, a3);
    }
    *(float4*)(att + row*EMBD + lane*4) = make_float4(a0,a1,a2,a3);
}

__global__ void store_f32(const float* __restrict__ X, float* __restrict__ o, long n){
    for(long i = (long)blockIdx.x*blockDim.x + threadIdx.x; i < n;
        i += (long)gridDim.x*blockDim.x)
        o[i] = X[i];
}

// ---------------- launch ----------------
extern "C" void kernel_launch(void* const* d_in, const int* in_sizes, int n_in,
                              void* d_out, int out_size, void* d_ws, size_t ws_size,
                              hipStream_t stream)
{
    if(n_in != 18) return;

    const float* x     = (const float*)d_in[0];
    const float* noise = (const float*)d_in[1];
    const float* Wproj = (const float*)d_in[2];
    const float* bproj = (const float*)d_in[3];
    const float* ctok  = (const float*)d_in[4];
    const float* ln1s  = (const float*)d_in[5];
    const float* ln1b  = (const float*)d_in[6];
    const float* Wq    = (const float*)d_in[7];
    const float* Wk    = (const float*)d_in[8];
    const float* Wv    = (const float*)d_in[9];
    const float* Wo    = (const float*)d_in[10];
    const float* bo    = (const float*)d_in[11];
    const float* ln2s  = (const float*)d_in[12];
    const float* ln2b  = (const float*)d_in[13];
    const float* W1    = (const float*)d_in[14];
    const float* b1    = (const float*)d_in[15];
    const float* W2    = (const float*)d_in[16];
    const float* b2    = (const float*)d_in[17];

    float* ws   = (float*)d_ws;
    float* bufH = ws;
    float* bufY = ws + (size_t)NTOK;
    float* bufA = ws + 2*(size_t)NTOK;
    float* bufB = ws + 3*(size_t)NTOK;
    float* kmax = ws + 4*(size_t)NTOK;
    float* ksum = kmax + BB*EMBD;
    float* ctxb = ksum + BB*EMBD;
    size_t need_bytes = (size_t)((ctxb + (size_t)BB*NHEAD*DH*DH) - ws) * sizeof(float);
    if(ws_size < need_bytes) return;

    // OUTPUTS ARE FLOAT32 (harness reads f32; r6 probe algebra proved this)
    float* out      = (float*)d_out;
    float* o_emb    = out;
    float* o_masked = out + (size_t)NTOK;
    float* o_h      = out + 2*(size_t)NTOK;
    float* o_mask   = out + 3*(size_t)NTOK;

    dim3 blk(256);
    dim3 tb(16,16);

    // spec (direct DFT) -> bufB [BSR][101]
    spec_kernel<<<BSR, blk, 0, stream>>>(x, bufB);
    // emb + epilogue + mask outputs, fully fused
    emb_kernel<<<BSR, blk, 0, stream>>>(bufB, Wproj, bproj, ctok, noise,
                                        bufH, o_emb, o_masked, o_mask);

    for(int l=0;l<NDEPTH;++l){
        const float* Wq_l = Wq + (size_t)l*EMBD*EMBD;
        const float* Wk_l = Wk + (size_t)l*EMBD*EMBD;
        const float* Wv_l = Wv + (size_t)l*EMBD*EMBD;
        const float* Wo_l = Wo + (size_t)l*EMBD*EMBD;
        const float* W1_l = W1 + (size_t)l*EMBD*HID;
        const float* W2_l = W2 + (size_t)l*HID*EMBD;

        ln_kernel<<<BSR/4, blk, 0, stream>>>(bufH, ln1s + l*EMBD, ln1b + l*EMBD, bufY);
        sgemm<0><<<dim3(16,6992), tb, 0, stream>>>(bufY, Wk_l, nullptr, bufA,
                                                   BSR, EMBD, EMBD, EMBD, EMBD, EMBD);
        sgemm<0><<<dim3(16,6992), tb, 0, stream>>>(bufY, Wv_l, nullptr, bufB,
                                                   BSR, EMBD, EMBD, EMBD, EMBD, EMBD);
        colstats<<<BB, blk, 0, stream>>>(bufA, kmax, ksum);
        ctx_kernel<<<BB*NHEAD, blk, 0, stream>>>(bufA, bufB, kmax, ksum, ctxb);
        sgemm<0><<<dim3(16,6992), tb, 0, stream>>>(bufY, Wq_l, nullptr, bufA,
                                                   BSR, EMBD, EMBD, EMBD, EMBD, EMBD);
        att_kernel<<<dim3(110, BB), blk, 0, stream>>>(bufA, ctxb, bufB);
        sgemm<1><<<dim3(16,6992), tb, 0, stream>>>(bufB, Wo_l, bo + l*EMBD, bufH,
                                                   BSR, EMBD, EMBD, EMBD, EMBD, EMBD);
        ln_kernel<<<BSR/4, blk, 0, stream>>>(bufH, ln2s + l*EMBD, ln2b + l*EMBD, bufY);
        for(int ch=0; ch<4; ++ch){
            size_t roff = (size_t)ch * (BSR/4) * EMBD;
            sgemm<2><<<dim3(64,1748), tb, 0, stream>>>(bufY + roff, W1_l, b1 + l*HID,
                bufA, BSR/4, HID, EMBD, EMBD, HID, HID);
            sgemm<1><<<dim3(16,1748), tb, 0, stream>>>(bufA, W2_l, b2 + l*EMBD,
                bufH + roff, BSR/4, EMBD, HID, HID, EMBD, EMBD);
        }
    }
    store_f32<<<4096, blk, 0, stream>>>(bufH, o_h, (long)NTOK);
}

// Round 9
// 6502.200 us; speedup vs baseline: 7.1123x; 7.1123x over previous
//
#include <hip/hip_runtime.h>

#define BB    256
#define NCH   23
#define TT    19
#define SS    437          // NCH*TT
#define BSR   111872       // BB*SS
#define EMBD  256
#define NHEAD 8
#define DH    32
#define NFREQ 101
#define NFFT  200
#define HOPSZ 100
#define TSLEN 2000
#define HID   1024
#define NDEPTH 4
#define NTOK  28639232     // BSR*EMBD

typedef __attribute__((ext_vector_type(8))) __bf16 bf16x8;
typedef __attribute__((ext_vector_type(4))) float  f32x4;

__device__ __forceinline__ float gelu_f(float x){
    return 0.5f*x*(1.0f + tanhf(0.7978845608028654f*(x + 0.044715f*x*x*x)));
}
__device__ __forceinline__ unsigned short f2b(float f){   // f32 -> bf16 RNE
    unsigned u = __float_as_uint(f);
    return (unsigned short)((u + 0x7FFFu + ((u >> 16) & 1u)) >> 16);
}

// ---------------- twiddle table [NFFT][NFREQ] float2(cos,sin) ----------------
__global__ void init_tw(float2* __restrict__ tw){
    int i = blockIdx.x*256 + threadIdx.x;
    if(i >= NFFT*NFREQ) return;
    int n = i / NFREQ, f = i % NFREQ;
    int ph = (n * f) % NFFT;
    float ang = 6.283185307179586f * (float)ph * (1.0f/(float)NFFT);
    float s, c; sincosf(ang, &s, &c);
    tw[i] = make_float2(c, s);
}

// ---------------- weight prep: transpose + bf16. Wt[n*K+k] = W[k*N+n] --------
__global__ void wprep(const float* __restrict__ W, unsigned short* __restrict__ Wt,
                      int K, int N){
    int i = blockIdx.x*256 + threadIdx.x;
    if(i >= N*K) return;
    int n = i / K, k = i % K;
    Wt[i] = f2b(W[(size_t)k*N + n]);
}

// ---------------- spectrogram via table: one block per frame ----------------
__global__ __launch_bounds__(256) void spec_kernel(const float* __restrict__ x,
    const float2* __restrict__ tw, float* __restrict__ spec)
{
    __shared__ float fr[NFFT];
    long row = blockIdx.x;              // row = (b*NCH+c)*TT + t
    int  t   = (int)(row % TT);
    long bc  = row / TT;
    int tid = threadIdx.x;
    if(tid < NFFT) fr[tid] = x[bc*(long)TSLEN + (long)t*HOPSZ + tid];
    __syncthreads();
    if(tid < NFREQ){
        float cs = 0.f, sn = 0.f;
        for(int n = 0; n < NFFT; ++n){
            float2 w = tw[n*NFREQ + tid];
            float xv = fr[n];
            cs = fmaf(xv, w.x, cs);
            sn = fmaf(xv, w.y, sn);
        }
        spec[row*NFREQ + tid] = sqrtf(cs*cs + sn*sn);
    }
}

// ---------------- fused emb projection + epilogue + mask outputs (f32) -------
__global__ __launch_bounds__(256) void emb_kernel(const float* __restrict__ spec,
    const float* __restrict__ Wp, const float* __restrict__ bp,
    const float* __restrict__ ctok, const float* __restrict__ noise,
    float* __restrict__ bufH, float* __restrict__ o_emb,
    float* __restrict__ o_masked, float* __restrict__ o_mask)
{
    __shared__ float sp[NFREQ];
    long row = blockIdx.x;
    int  t   = (int)(row % TT);
    long rg  = row / TT;
    int  c   = (int)(rg % NCH);
    int  e   = threadIdx.x;
    if(e < NFREQ) sp[e] = spec[row*NFREQ + e];
    __syncthreads();
    int j = e >> 1;
    float div = expf((float)(2*j) * (-9.210340371976184f/256.0f));
    float ang = (float)t * div;
    float acc = bp[e] + ctok[c*EMBD + e] + ((e & 1) ? cosf(ang) : sinf(ang));
    for(int k = 0; k < NFREQ; ++k)
        acc = fmaf(sp[k], Wp[k*EMBD + e], acc);
    long i = row*EMBD + e;
    o_emb[i] = acc;
    float mn = noise[i];
    bool  m  = mn < 0.9f;
    float md = m ? 0.0f : acc;
    bufH[i]     = md;
    o_masked[i] = md;
    o_mask[i]   = m ? 1.0f : 0.0f;
}

// ---------------- MFMA bf16 GEMM: C[m,n] = sum_k A[m,k]*Bt[n,k] --------------
// A bf16 [M][K], Bt bf16 [N][K] (pre-transposed weight), K%64==0, M%128==0, N%128==0.
// MODE 0: Cf32 = acc ; MODE 1: Cf32 += acc + bias[n] ; MODE 2: Cbf16 = gelu(acc+bias[n])
template<int MODE>
__global__ __launch_bounds__(256) void gemm_mfma(
    const unsigned short* __restrict__ A, const unsigned short* __restrict__ Bt,
    const float* __restrict__ bias, void* __restrict__ Cv,
    int M, int N, int K)
{
    __shared__ __align__(16) unsigned short As[128*64];
    __shared__ __align__(16) unsigned short Bs[128*64];
    const int tid = threadIdx.x;
    const int w = tid >> 6, l = tid & 63;
    const int m0 = blockIdx.y * 128, n0 = blockIdx.x * 128;
    const int wr = w >> 1, wc = w & 1;               // wave's 64x64 sub-tile
    f32x4 acc[4][4];
    #pragma unroll
    for(int i=0;i<4;++i)
        #pragma unroll
        for(int jj=0;jj<4;++jj) acc[i][jj] = (f32x4){0.f,0.f,0.f,0.f};

    const int srow0 = w*32 + (l>>3);                 // staging row (+ it*8)
    const int sgrp  = l & 7;                         // staging 16B-group within row

    for(int k0 = 0; k0 < K; k0 += 64){
        #pragma unroll
        for(int it=0; it<4; ++it){
            int row  = srow0 + it*8;
            int colA = ((sgrp ^ (row & 7)) << 3);    // pre-swizzled source col
            const unsigned short* ga = A  + (size_t)(m0+row)*K + k0 + colA;
            const unsigned short* gb = Bt + (size_t)(n0+row)*K + k0 + colA;
            __builtin_amdgcn_global_load_lds(
                (__attribute__((address_space(1))) void*)ga,
                (__attribute__((address_space(3))) void*)(As + w*2048 + it*512),
                16, 0, 0);
            __builtin_amdgcn_global_load_lds(
                (__attribute__((address_space(1))) void*)gb,
                (__attribute__((address_space(3))) void*)(Bs + w*2048 + it*512),
                16, 0, 0);
        }
        __syncthreads();                              // drains vmcnt + barrier
        #pragma unroll
        for(int kk=0; kk<2; ++kk){
            bf16x8 af[4], bfr[4];
            #pragma unroll
            for(int mi=0;mi<4;++mi){
                int row = wr*64 + mi*16 + (l & 15);
                int grp = kk*4 + (l >> 4);
                af[mi] = *(const bf16x8*)&As[row*64 + ((grp ^ (row&7))<<3)];
            }
            #pragma unroll
            for(int ni=0;ni<4;++ni){
                int row = wc*64 + ni*16 + (l & 15);
                int grp = kk*4 + (l >> 4);
                bfr[ni] = *(const bf16x8*)&Bs[row*64 + ((grp ^ (row&7))<<3)];
            }
            #pragma unroll
            for(int mi=0;mi<4;++mi)
                #pragma unroll
                for(int ni=0;ni<4;++ni)
                    acc[mi][ni] = __builtin_amdgcn_mfma_f32_16x16x32_bf16(
                        af[mi], bfr[ni], acc[mi][ni], 0, 0, 0);
        }
        __syncthreads();
    }
    const int cn  = l & 15;
    const int cr4 = (l >> 4) * 4;
    if(MODE == 2){
        unsigned short* C = (unsigned short*)Cv;
        #pragma unroll
        for(int ni=0;ni<4;++ni){
            int n = n0 + wc*64 + ni*16 + cn;
            float bn = bias[n];
            #pragma unroll
            for(int mi=0;mi<4;++mi){
                int mB = m0 + wr*64 + mi*16 + cr4;
                #pragma unroll
                for(int r=0;r<4;++r)
                    C[(size_t)(mB+r)*N + n] = f2b(gelu_f(acc[mi][ni][r] + bn));
            }
        }
    } else {
        float* C = (float*)Cv;
        #pragma unroll
        for(int ni=0;ni<4;++ni){
            int n = n0 + wc*64 + ni*16 + cn;
            float bn = (MODE==1) ? bias[n] : 0.0f;
            #pragma unroll
            for(int mi=0;mi<4;++mi){
                int mB = m0 + wr*64 + mi*16 + cr4;
                #pragma unroll
                for(int r=0;r<4;++r){
                    size_t off = (size_t)(mB+r)*N + n;
                    if(MODE==0) C[off] = acc[mi][ni][r];
                    else        C[off] = C[off] + acc[mi][ni][r] + bn;
                }
            }
        }
    }
}

// ---------------- layernorm (wave per row) -> bf16 out ----------------
__global__ __launch_bounds__(256) void ln_bf16(const float* __restrict__ X,
    const float* __restrict__ s, const float* __restrict__ b,
    unsigned short* __restrict__ Y)
{
    int w = threadIdx.x >> 6, lane = threadIdx.x & 63;
    long row = (long)blockIdx.x*4 + w;
    const float* xr = X + row*EMBD;
    float4 v = *(const float4*)(xr + lane*4);
    float sum = v.x + v.y + v.z + v.w;
    #pragma unroll
    for(int o=32;o>0;o>>=1) sum += __shfl_xor(sum, o, 64);
    float mu = sum * (1.0f/256.0f);
    float dx = v.x-mu, dy = v.y-mu, dz = v.z-mu, dw = v.w-mu;
    float vs = dx*dx + dy*dy + dz*dz + dw*dw;
    #pragma unroll
    for(int o=32;o>0;o>>=1) vs += __shfl_xor(vs, o, 64);
    float rstd = rsqrtf(vs*(1.0f/256.0f) + 1e-5f);
    float4 s4 = *(const float4*)(s + lane*4);
    float4 b4 = *(const float4*)(b + lane*4);
    ushort4 o4;
    o4.x = f2b(dx*rstd*s4.x + b4.x);
    o4.y = f2b(dy*rstd*s4.y + b4.y);
    o4.z = f2b(dz*rstd*s4.z + b4.z);
    o4.w = f2b(dw*rstd*s4.w + b4.w);
    *(ushort4*)(Y + row*EMBD + lane*4) = o4;
}

// ---------------- k-softmax column stats over S ----------------
__global__ void colstats(const float* __restrict__ klog, float* __restrict__ kmax,
                         float* __restrict__ ksum)
{
    int b = blockIdx.x, c = threadIdx.x;
    const float* p = klog + (long)b*SS*EMBD + c;
    float m = -1e30f, sacc = 0.f;
    for(int n=0;n<SS;++n){
        float x = p[(long)n*EMBD];
        if(x > m){ sacc = sacc*expf(m-x) + 1.0f; m = x; }
        else     { sacc += expf(x-m); }
    }
    kmax[b*EMBD+c] = m;
    ksum[b*EMBD+c] = sacc;
}

// ---------------- ctx[b,h,d,e] = sum_n softmax_S(k)[n,d] * v[n,e] ------------
__global__ __launch_bounds__(256) void ctx_kernel(const float* __restrict__ klog,
    const float* __restrict__ v, const float* __restrict__ kmax,
    const float* __restrict__ ksum, float* __restrict__ ctx)
{
    __shared__ float kt[16][DH], vt[16][DH];
    int bh = blockIdx.x; int b = bh >> 3, h = bh & 7;
    int tid = threadIdx.x;
    int d = tid >> 3, e4 = (tid & 7) * 4;
    float km = kmax[b*EMBD + h*DH + d];
    float a0=0,a1=0,a2=0,a3=0;
    for(int n0=0;n0<SS;n0+=16){
        __syncthreads();
        #pragma unroll
        for(int i=0;i<2;++i){
            int e = tid + i*256;
            int nn = e >> 5, dd = e & 31;
            int n = n0 + nn;
            float kv, vv;
            if(n < SS){
                long off = ((long)(b*SS+n))*EMBD + h*DH + dd;
                kv = klog[off];
                vv = v[off];
            } else { kv = -1e30f; vv = 0.f; }
            kt[nn][dd] = kv; vt[nn][dd] = vv;
        }
        __syncthreads();
        #pragma unroll
        for(int nn=0;nn<16;++nn){
            float ke = expf(kt[nn][d] - km);
            a0 = fmaf(ke, vt[nn][e4+0], a0);
            a1 = fmaf(ke, vt[nn][e4+1], a1);
            a2 = fmaf(ke, vt[nn][e4+2], a2);
            a3 = fmaf(ke, vt[nn][e4+3], a3);
        }
    }
    float inv = 1.0f / ksum[b*EMBD + h*DH + d];
    float* op = ctx + ((long)bh*DH + d)*DH + e4;
    op[0]=a0*inv; op[1]=a1*inv; op[2]=a2*inv; op[3]=a3*inv;
}

// ---------------- per-token q-softmax + att = q @ ctx -> bf16 ----------------
__global__ __launch_bounds__(256) void att_kernel(const float* __restrict__ qlog,
    const float* __restrict__ ctx, unsigned short* __restrict__ att)
{
    __shared__ float qs[4][EMBD];
    int w = threadIdx.x >> 6, lane = threadIdx.x & 63;
    int b = blockIdx.y;
    int s = blockIdx.x*4 + w;
    if(s >= SS) return;
    long row = (long)b*SS + s;
    float4 q4 = *(const float4*)(qlog + row*EMBD + lane*4);
    float m = fmaxf(fmaxf(q4.x,q4.y), fmaxf(q4.z,q4.w));
    #pragma unroll
    for(int o=1;o<8;o<<=1) m = fmaxf(m, __shfl_xor(m, o, 64));
    float e0 = expf(q4.x-m), e1 = expf(q4.y-m), e2 = expf(q4.z-m), e3 = expf(q4.w-m);
    float ssum = e0+e1+e2+e3;
    #pragma unroll
    for(int o=1;o<8;o<<=1) ssum += __shfl_xor(ssum, o, 64);
    float sc = 0.17677669529663687f / ssum;
    *(float4*)&qs[w][lane*4] = make_float4(e0*sc, e1*sc, e2*sc, e3*sc);
    int head = lane >> 3;
    int ecol = (lane & 7) * 4;
    const float* cb = ctx + ((long)(b*NHEAD + head))*DH*DH + ecol;
    float a0=0,a1=0,a2=0,a3=0;
    #pragma unroll
    for(int d=0; d<DH; ++d){
        float qd = qs[w][head*DH + d];
        float4 c4 = *(const float4*)(cb + d*DH);
        a0 = fmaf(qd, c4.x, a0);
        a1 = fmaf(qd, c4.y, a1);
        a2 = fmaf(qd, c4.z, a2);
        a3 = fmaf(qd, c4.w, a3);
    }
    ushort4 o4; o4.x=f2b(a0); o4.y=f2b(a1); o4.z=f2b(a2); o4.w=f2b(a3);
    *(ushort4*)(att + row*EMBD + lane*4) = o4;
}

__global__ void store_f32(const float* __restrict__ X, float* __restrict__ o, long n){
    for(long i = (long)blockIdx.x*blockDim.x + threadIdx.x; i < n;
        i += (long)gridDim.x*blockDim.x)
        o[i] = X[i];
}

// ---------------- launch ----------------
extern "C" void kernel_launch(void* const* d_in, const int* in_sizes, int n_in,
                              void* d_out, int out_size, void* d_ws, size_t ws_size,
                              hipStream_t stream)
{
    if(n_in != 18) return;

    const float* x     = (const float*)d_in[0];
    const float* noise = (const float*)d_in[1];
    const float* Wproj = (const float*)d_in[2];
    const float* bproj = (const float*)d_in[3];
    const float* ctok  = (const float*)d_in[4];
    const float* ln1s  = (const float*)d_in[5];
    const float* ln1b  = (const float*)d_in[6];
    const float* Wq    = (const float*)d_in[7];
    const float* Wk    = (const float*)d_in[8];
    const float* Wv    = (const float*)d_in[9];
    const float* Wo    = (const float*)d_in[10];
    const float* bo    = (const float*)d_in[11];
    const float* ln2s  = (const float*)d_in[12];
    const float* ln2b  = (const float*)d_in[13];
    const float* W1    = (const float*)d_in[14];
    const float* b1    = (const float*)d_in[15];
    const float* W2    = (const float*)d_in[16];
    const float* b2    = (const float*)d_in[17];

    float* ws   = (float*)d_ws;
    float* bufH = ws;                              // f32 residual [NTOK]
    float* bufA = ws + (size_t)NTOK;               // f32 k/q logits; also spec & hidden
    float* bufB = ws + 2*(size_t)NTOK;             // f32 v logits; also att-bf16 & hidden
    unsigned short* bufYb = (unsigned short*)(ws + 3*(size_t)NTOK); // bf16 ln out [NTOK]
    float* kmax = ws + 3*(size_t)NTOK + (size_t)NTOK/2;
    float* ksum = kmax + BB*EMBD;
    float* ctxb = ksum + BB*EMBD;
    unsigned short* wbuf = (unsigned short*)(ctxb + (size_t)BB*NHEAD*DH*DH);
    const size_t WL = 786432;                      // bf16 weights per layer
    float2* twb = (float2*)(wbuf + 4*WL);
    size_t need_bytes = ((char*)(twb + NFFT*NFREQ)) - (char*)d_ws;
    if(ws_size < need_bytes) return;

    float* spec   = bufA;                          // [BSR][101] f32 (pre-layer phase)
    unsigned short* bufAtt = (unsigned short*)bufB;// bf16 att out (after v dead)
    unsigned short* bufHid = (unsigned short*)bufA;// bf16 hidden [M][1024] spans A+B

    float* out      = (float*)d_out;
    float* o_emb    = out;
    float* o_masked = out + (size_t)NTOK;
    float* o_h      = out + 2*(size_t)NTOK;
    float* o_mask   = out + 3*(size_t)NTOK;

    dim3 blk(256);

    // ---- prep: twiddle table + bf16-transposed weights ----
    init_tw<<<(NFFT*NFREQ+255)/256, blk, 0, stream>>>(twb);
    for(int l=0;l<NDEPTH;++l){
        unsigned short* wl = wbuf + (size_t)l*WL;
        wprep<<<256,  blk, 0, stream>>>(Wq + (size_t)l*65536,  wl,            256, 256);
        wprep<<<256,  blk, 0, stream>>>(Wk + (size_t)l*65536,  wl + 65536,    256, 256);
        wprep<<<256,  blk, 0, stream>>>(Wv + (size_t)l*65536,  wl + 131072,   256, 256);
        wprep<<<256,  blk, 0, stream>>>(Wo + (size_t)l*65536,  wl + 196608,   256, 256);
        wprep<<<1024, blk, 0, stream>>>(W1 + (size_t)l*262144, wl + 262144,   256, 1024);
        wprep<<<1024, blk, 0, stream>>>(W2 + (size_t)l*262144, wl + 524288,   1024, 256);
    }

    // ---- front end ----
    spec_kernel<<<BSR, blk, 0, stream>>>(x, twb, spec);
    emb_kernel<<<BSR, blk, 0, stream>>>(spec, Wproj, bproj, ctok, noise,
                                        bufH, o_emb, o_masked, o_mask);

    // ---- transformer layers ----
    for(int l=0;l<NDEPTH;++l){
        unsigned short* wl  = wbuf + (size_t)l*WL;
        unsigned short* Wqt = wl;
        unsigned short* Wkt = wl + 65536;
        unsigned short* Wvt = wl + 131072;
        unsigned short* Wot = wl + 196608;
        unsigned short* W1t = wl + 262144;
        unsigned short* W2t = wl + 524288;

        ln_bf16<<<BSR/4, blk, 0, stream>>>(bufH, ln1s + l*EMBD, ln1b + l*EMBD, bufYb);
        gemm_mfma<0><<<dim3(2,874), blk, 0, stream>>>(bufYb, Wkt, nullptr, bufA,
                                                      BSR, EMBD, EMBD);
        gemm_mfma<0><<<dim3(2,874), blk, 0, stream>>>(bufYb, Wvt, nullptr, bufB,
                                                      BSR, EMBD, EMBD);
        colstats<<<BB, blk, 0, stream>>>(bufA, kmax, ksum);
        ctx_kernel<<<BB*NHEAD, blk, 0, stream>>>(bufA, bufB, kmax, ksum, ctxb);
        gemm_mfma<0><<<dim3(2,874), blk, 0, stream>>>(bufYb, Wqt, nullptr, bufA,
                                                      BSR, EMBD, EMBD);
        att_kernel<<<dim3(110, BB), blk, 0, stream>>>(bufA, ctxb, bufAtt);
        gemm_mfma<1><<<dim3(2,874), blk, 0, stream>>>(bufAtt, Wot, bo + l*EMBD, bufH,
                                                      BSR, EMBD, EMBD);
        ln_bf16<<<BSR/4, blk, 0, stream>>>(bufH, ln2s + l*EMBD, ln2b + l*EMBD, bufYb);
        gemm_mfma<2><<<dim3(8,874), blk, 0, stream>>>(bufYb, W1t, b1 + l*HID, bufHid,
                                                      BSR, HID, EMBD);
        gemm_mfma<1><<<dim3(2,874), blk, 0, stream>>>(bufHid, W2t, b2 + l*EMBD, bufH,
                                                      BSR, EMBD, HID);
    }
    store_f32<<<4096, blk, 0, stream>>>(bufH, o_h, (long)NTOK);
}

// Round 10
// 4710.664 us; speedup vs baseline: 9.8172x; 1.3803x over previous
//
#include <hip/hip_runtime.h>

#define BB    256
#define NCH   23
#define TT    19
#define SS    437          // NCH*TT
#define BSR   111872       // BB*SS
#define EMBD  256
#define NHEAD 8
#define DH    32
#define NFREQ 101
#define NFFT  200
#define HOPSZ 100
#define TSLEN 2000
#define HID   1024
#define NDEPTH 4
#define NTOK  28639232     // BSR*EMBD
#define QKVW  768

typedef __attribute__((ext_vector_type(8))) __bf16 bf16x8;
typedef __attribute__((ext_vector_type(4))) float  f32x4;

__device__ __forceinline__ float gelu_f(float x){
    return 0.5f*x*(1.0f + tanhf(0.7978845608028654f*(x + 0.044715f*x*x*x)));
}
__device__ __forceinline__ unsigned short f2b(float f){   // f32 -> bf16 RNE
    unsigned u = __float_as_uint(f);
    return (unsigned short)((u + 0x7FFFu + ((u >> 16) & 1u)) >> 16);
}
__device__ __forceinline__ float b2f(unsigned short h){
    return __uint_as_float(((unsigned)h) << 16);
}

// ---------------- DFT table bf16 [256][256]: row n = output col ----------------
// rows 0..100: cos(2pi*(n*k mod 200)/200), rows 128..228: sin(f=n-128), else 0
__global__ void init_twb(unsigned short* __restrict__ tw){
    int i = blockIdx.x*256 + threadIdx.x;
    if(i >= 256*256) return;
    int n = i >> 8, k = i & 255;
    float v = 0.f;
    if(k < NFFT){
        if(n <= 100){
            int ph = (n * k) % NFFT;
            v = cosf(6.283185307179586f * (float)ph / (float)NFFT);
        } else if(n >= 128 && n <= 228){
            int ph = ((n - 128) * k) % NFFT;
            v = sinf(6.283185307179586f * (float)ph / (float)NFFT);
        }
    }
    tw[i] = f2b(v);
}

// posenc table f32 [TT][EMBD]
__global__ void init_pe(float* __restrict__ pe){
    int i = blockIdx.x*256 + threadIdx.x;
    if(i >= TT*EMBD) return;
    int t = i / EMBD, e = i % EMBD;
    int j = e >> 1;
    float div = expf((float)(2*j) * (-9.210340371976184f/256.0f));
    float ang = (float)t * div;
    pe[i] = (e & 1) ? cosf(ang) : sinf(ang);
}

// W_proj -> bf16 transposed+padded [256][128]: Wt[e][k] = Wp[k*256+e] (k<101)
__global__ void wprep_proj(const float* __restrict__ Wp, unsigned short* __restrict__ Wt){
    int i = blockIdx.x*256 + threadIdx.x;
    if(i >= 256*128) return;
    int e = i >> 7, k = i & 127;
    Wt[i] = f2b(k < NFREQ ? Wp[(size_t)k*EMBD + e] : 0.f);
}

// generic weight transpose+bf16: Wt[n*K+k] = W[k*N+n]
__global__ void wprep(const float* __restrict__ W, unsigned short* __restrict__ Wt,
                      int K, int N){
    int i = blockIdx.x*256 + threadIdx.x;
    if(i >= N*K) return;
    int n = i / K, k = i % K;
    Wt[i] = f2b(W[(size_t)k*N + n]);
}

// frames bf16 [BSR][256]: k<200 -> x sample, else 0
__global__ void frames_bf16(const float* __restrict__ x, unsigned short* __restrict__ fr){
    for(long i = (long)blockIdx.x*blockDim.x + threadIdx.x; i < (long)BSR*256;
        i += (long)gridDim.x*blockDim.x){
        int  k   = (int)(i & 255);
        long row = i >> 8;
        int  t   = (int)(row % TT);
        long bc  = row / TT;
        float v = (k < NFFT) ? x[bc*(long)TSLEN + (long)t*HOPSZ + k] : 0.f;
        fr[i] = f2b(v);
    }
}

// spec bf16 [BSR][128] from dft f32 [BSR][256]
__global__ void combine_bf16(const float* __restrict__ dft, unsigned short* __restrict__ sp){
    for(long i = (long)blockIdx.x*blockDim.x + threadIdx.x; i < (long)BSR*128;
        i += (long)gridDim.x*blockDim.x){
        int  f   = (int)(i & 127);
        long row = i >> 7;
        float v = 0.f;
        if(f < NFREQ){
            float c = dft[row*256 + f];
            float s = dft[row*256 + 128 + f];
            v = sqrtf(c*c + s*s);
        }
        sp[i] = f2b(v);
    }
}

// ---------------- MFMA bf16 GEMM core (128x128 tile, BK=64) ------------------
// A bf16 [M][K], Bt bf16 [N][K]. K%64==0, M%128==0, N%128==0.
// MODE 0: Cf32 = acc ; MODE 1: Cf32 += acc + bias ; MODE 2: Cbf16 = gelu(acc+bias)
// MODE 3: Cbf16 = acc
template<int MODE>
__global__ __launch_bounds__(256) void gemm_mfma(
    const unsigned short* __restrict__ A, const unsigned short* __restrict__ Bt,
    const float* __restrict__ bias, void* __restrict__ Cv,
    int M, int N, int K)
{
    __shared__ __align__(16) unsigned short As[128*64];
    __shared__ __align__(16) unsigned short Bs[128*64];
    const int tid = threadIdx.x;
    const int w = tid >> 6, l = tid & 63;
    const int m0 = blockIdx.y * 128, n0 = blockIdx.x * 128;
    const int wr = w >> 1, wc = w & 1;
    f32x4 acc[4][4];
    #pragma unroll
    for(int i=0;i<4;++i)
        #pragma unroll
        for(int jj=0;jj<4;++jj) acc[i][jj] = (f32x4){0.f,0.f,0.f,0.f};

    const int srow0 = w*32 + (l>>3);
    const int sgrp  = l & 7;

    for(int k0 = 0; k0 < K; k0 += 64){
        #pragma unroll
        for(int it=0; it<4; ++it){
            int row  = srow0 + it*8;
            int colA = ((sgrp ^ (row & 7)) << 3);
            const unsigned short* ga = A  + (size_t)(m0+row)*K + k0 + colA;
            const unsigned short* gb = Bt + (size_t)(n0+row)*K + k0 + colA;
            __builtin_amdgcn_global_load_lds(
                (__attribute__((address_space(1))) void*)ga,
                (__attribute__((address_space(3))) void*)(As + w*2048 + it*512),
                16, 0, 0);
            __builtin_amdgcn_global_load_lds(
                (__attribute__((address_space(1))) void*)gb,
                (__attribute__((address_space(3))) void*)(Bs + w*2048 + it*512),
                16, 0, 0);
        }
        __syncthreads();
        #pragma unroll
        for(int kk=0; kk<2; ++kk){
            bf16x8 af[4], bfr[4];
            #pragma unroll
            for(int mi=0;mi<4;++mi){
                int row = wr*64 + mi*16 + (l & 15);
                int grp = kk*4 + (l >> 4);
                af[mi] = *(const bf16x8*)&As[row*64 + ((grp ^ (row&7))<<3)];
            }
            #pragma unroll
            for(int ni=0;ni<4;++ni){
                int row = wc*64 + ni*16 + (l & 15);
                int grp = kk*4 + (l >> 4);
                bfr[ni] = *(const bf16x8*)&Bs[row*64 + ((grp ^ (row&7))<<3)];
            }
            #pragma unroll
            for(int mi=0;mi<4;++mi)
                #pragma unroll
                for(int ni=0;ni<4;++ni)
                    acc[mi][ni] = __builtin_amdgcn_mfma_f32_16x16x32_bf16(
                        af[mi], bfr[ni], acc[mi][ni], 0, 0, 0);
        }
        __syncthreads();
    }
    const int cn  = l & 15;
    const int cr4 = (l >> 4) * 4;
    if(MODE == 2 || MODE == 3){
        unsigned short* C = (unsigned short*)Cv;
        #pragma unroll
        for(int ni=0;ni<4;++ni){
            int n = n0 + wc*64 + ni*16 + cn;
            float bn = (MODE==2) ? bias[n] : 0.f;
            #pragma unroll
            for(int mi=0;mi<4;++mi){
                int mB = m0 + wr*64 + mi*16 + cr4;
                #pragma unroll
                for(int r=0;r<4;++r){
                    float v = acc[mi][ni][r];
                    C[(size_t)(mB+r)*N + n] = f2b(MODE==2 ? gelu_f(v + bn) : v);
                }
            }
        }
    } else {
        float* C = (float*)Cv;
        #pragma unroll
        for(int ni=0;ni<4;++ni){
            int n = n0 + wc*64 + ni*16 + cn;
            float bn = (MODE==1) ? bias[n] : 0.0f;
            #pragma unroll
            for(int mi=0;mi<4;++mi){
                int mB = m0 + wr*64 + mi*16 + cr4;
                #pragma unroll
                for(int r=0;r<4;++r){
                    size_t off = (size_t)(mB+r)*N + n;
                    if(MODE==0) C[off] = acc[mi][ni][r];
                    else        C[off] = C[off] + acc[mi][ni][r] + bn;
                }
            }
        }
    }
}

// ---------------- emb GEMM: spec_b @ Wpb + full fused epilogue ---------------
// A [BSR][128] bf16, Bt [256][128] bf16. Epilogue: +bias+ctok+pe, write o_emb,
// o_masked, o_mask (f32) and bufH (masked, f32).
__global__ __launch_bounds__(256) void gemm_emb(
    const unsigned short* __restrict__ A, const unsigned short* __restrict__ Bt,
    const float* __restrict__ bp, const float* __restrict__ ctok,
    const float* __restrict__ pe, const float* __restrict__ noise,
    float* __restrict__ o_emb, float* __restrict__ o_masked,
    float* __restrict__ o_mask, float* __restrict__ bufH)
{
    const int K = 128, N = 256;
    __shared__ __align__(16) unsigned short As[128*64];
    __shared__ __align__(16) unsigned short Bs[128*64];
    const int tid = threadIdx.x;
    const int w = tid >> 6, l = tid & 63;
    const int m0 = blockIdx.y * 128, n0 = blockIdx.x * 128;
    const int wr = w >> 1, wc = w & 1;
    f32x4 acc[4][4];
    #pragma unroll
    for(int i=0;i<4;++i)
        #pragma unroll
        for(int jj=0;jj<4;++jj) acc[i][jj] = (f32x4){0.f,0.f,0.f,0.f};
    const int srow0 = w*32 + (l>>3);
    const int sgrp  = l & 7;
    for(int k0 = 0; k0 < K; k0 += 64){
        #pragma unroll
        for(int it=0; it<4; ++it){
            int row  = srow0 + it*8;
            int colA = ((sgrp ^ (row & 7)) << 3);
            const unsigned short* ga = A  + (size_t)(m0+row)*K + k0 + colA;
            const unsigned short* gb = Bt + (size_t)(n0+row)*K + k0 + colA;
            __builtin_amdgcn_global_load_lds(
                (__attribute__((address_space(1))) void*)ga,
                (__attribute__((address_space(3))) void*)(As + w*2048 + it*512),
                16, 0, 0);
            __builtin_amdgcn_global_load_lds(
                (__attribute__((address_space(1))) void*)gb,
                (__attribute__((address_space(3))) void*)(Bs + w*2048 + it*512),
                16, 0, 0);
        }
        __syncthreads();
        #pragma unroll
        for(int kk=0; kk<2; ++kk){
            bf16x8 af[4], bfr[4];
            #pragma unroll
            for(int mi=0;mi<4;++mi){
                int row = wr*64 + mi*16 + (l & 15);
                int grp = kk*4 + (l >> 4);
                af[mi] = *(const bf16x8*)&As[row*64 + ((grp ^ (row&7))<<3)];
            }
            #pragma unroll
            for(int ni=0;ni<4;++ni){
                int row = wc*64 + ni*16 + (l & 15);
                int grp = kk*4 + (l >> 4);
                bfr[ni] = *(const bf16x8*)&Bs[row*64 + ((grp ^ (row&7))<<3)];
            }
            #pragma unroll
            for(int mi=0;mi<4;++mi)
                #pragma unroll
                for(int ni=0;ni<4;++ni)
                    acc[mi][ni] = __builtin_amdgcn_mfma_f32_16x16x32_bf16(
                        af[mi], bfr[ni], acc[mi][ni], 0, 0, 0);
        }
        __syncthreads();
    }
    const int cn  = l & 15;
    const int cr4 = (l >> 4) * 4;
    #pragma unroll
    for(int ni=0;ni<4;++ni){
        int n = n0 + wc*64 + ni*16 + cn;
        float bn = bp[n];
        #pragma unroll
        for(int mi=0;mi<4;++mi){
            int mB = m0 + wr*64 + mi*16 + cr4;
            #pragma unroll
            for(int r=0;r<4;++r){
                int m = mB + r;
                int t = m % TT;
                int c = (m / TT) % NCH;
                size_t off = (size_t)m*EMBD + n;
                float v = acc[mi][ni][r] + bn + ctok[c*EMBD + n] + pe[t*EMBD + n];
                o_emb[off] = v;
                float mn = noise[off];
                bool  msk = mn < 0.9f;
                float md = msk ? 0.f : v;
                bufH[off]     = md;
                o_masked[off] = md;
                o_mask[off]   = msk ? 1.f : 0.f;
            }
        }
    }
}

// ---------------- layernorm (wave per row) -> bf16 out ----------------
__global__ __launch_bounds__(256) void ln_bf16(const float* __restrict__ X,
    const float* __restrict__ s, const float* __restrict__ b,
    unsigned short* __restrict__ Y)
{
    int w = threadIdx.x >> 6, lane = threadIdx.x & 63;
    long row = (long)blockIdx.x*4 + w;
    const float* xr = X + row*EMBD;
    float4 v = *(const float4*)(xr + lane*4);
    float sum = v.x + v.y + v.z + v.w;
    #pragma unroll
    for(int o=32;o>0;o>>=1) sum += __shfl_xor(sum, o, 64);
    float mu = sum * (1.0f/256.0f);
    float dx = v.x-mu, dy = v.y-mu, dz = v.z-mu, dw = v.w-mu;
    float vs = dx*dx + dy*dy + dz*dz + dw*dw;
    #pragma unroll
    for(int o=32;o>0;o>>=1) vs += __shfl_xor(vs, o, 64);
    float rstd = rsqrtf(vs*(1.0f/256.0f) + 1e-5f);
    float4 s4 = *(const float4*)(s + lane*4);
    float4 b4 = *(const float4*)(b + lane*4);
    ushort4 o4;
    o4.x = f2b(dx*rstd*s4.x + b4.x);
    o4.y = f2b(dy*rstd*s4.y + b4.y);
    o4.z = f2b(dz*rstd*s4.z + b4.z);
    o4.w = f2b(dw*rstd*s4.w + b4.w);
    *(ushort4*)(Y + row*EMBD + lane*4) = o4;
}

// ---------------- k-softmax column stats (k = qkvb cols 256..511) ------------
__global__ void colstats(const unsigned short* __restrict__ qkvb,
                         float* __restrict__ kmax, float* __restrict__ ksum)
{
    int b = blockIdx.x, c = threadIdx.x;
    const unsigned short* p = qkvb + (size_t)b*SS*QKVW + 256 + c;
    float m = -1e30f, sacc = 0.f;
    for(int n=0;n<SS;++n){
        float x = b2f(p[(size_t)n*QKVW]);
        if(x > m){ sacc = sacc*expf(m-x) + 1.0f; m = x; }
        else     { sacc += expf(x-m); }
    }
    kmax[b*EMBD+c] = m;
    ksum[b*EMBD+c] = sacc;
}

// ---------------- ctx[b,h,d,e] = sum_n softmax_S(k)[n,d] * v[n,e] ------------
__global__ __launch_bounds__(256) void ctx_kernel(const unsigned short* __restrict__ qkvb,
    const float* __restrict__ kmax, const float* __restrict__ ksum,
    float* __restrict__ ctx)
{
    __shared__ float kt[16][DH], vt[16][DH];
    int bh = blockIdx.x; int b = bh >> 3, h = bh & 7;
    int tid = threadIdx.x;
    int d = tid >> 3, e4 = (tid & 7) * 4;
    float km = kmax[b*EMBD + h*DH + d];
    float a0=0,a1=0,a2=0,a3=0;
    for(int n0=0;n0<SS;n0+=16){
        __syncthreads();
        #pragma unroll
        for(int i=0;i<2;++i){
            int e = tid + i*256;
            int nn = e >> 5, dd = e & 31;
            int n = n0 + nn;
            float kv, vv;
            if(n < SS){
                size_t off = ((size_t)(b*SS+n))*QKVW + h*DH + dd;
                kv = b2f(qkvb[off + 256]);
                vv = b2f(qkvb[off + 512]);
            } else { kv = -1e30f; vv = 0.f; }
            kt[nn][dd] = kv; vt[nn][dd] = vv;
        }
        __syncthreads();
        #pragma unroll
        for(int nn=0;nn<16;++nn){
            float ke = expf(kt[nn][d] - km);
            a0 = fmaf(ke, vt[nn][e4+0], a0);
            a1 = fmaf(ke, vt[nn][e4+1], a1);
            a2 = fmaf(ke, vt[nn][e4+2], a2);
            a3 = fmaf(ke, vt[nn][e4+3], a3);
        }
    }
    float inv = 1.0f / ksum[b*EMBD + h*DH + d];
    float* op = ctx + ((size_t)bh*DH + d)*DH + e4;
    op[0]=a0*inv; op[1]=a1*inv; op[2]=a2*inv; op[3]=a3*inv;
}

// ---------------- per-token q-softmax + att = q @ ctx -> bf16 ----------------
__global__ __launch_bounds__(256) void att_kernel(const unsigned short* __restrict__ qkvb,
    const float* __restrict__ ctx, unsigned short* __restrict__ att)
{
    __shared__ float qs[4][EMBD];
    int w = threadIdx.x >> 6, lane = threadIdx.x & 63;
    int b = blockIdx.y;
    int s = blockIdx.x*4 + w;
    if(s >= SS) return;
    long row = (long)b*SS + s;
    ushort4 qu = *(const ushort4*)(qkvb + (size_t)row*QKVW + lane*4);
    float4 q4 = make_float4(b2f(qu.x), b2f(qu.y), b2f(qu.z), b2f(qu.w));
    float m = fmaxf(fmaxf(q4.x,q4.y), fmaxf(q4.z,q4.w));
    #pragma unroll
    for(int o=1;o<8;o<<=1) m = fmaxf(m, __shfl_xor(m, o, 64));
    float e0 = expf(q4.x-m), e1 = expf(q4.y-m), e2 = expf(q4.z-m), e3 = expf(q4.w-m);
    float ssum = e0+e1+e2+e3;
    #pragma unroll
    for(int o=1;o<8;o<<=1) ssum += __shfl_xor(ssum, o, 64);
    float sc = 0.17677669529663687f / ssum;
    *(float4*)&qs[w][lane*4] = make_float4(e0*sc, e1*sc, e2*sc, e3*sc);
    int head = lane >> 3;
    int ecol = (lane & 7) * 4;
    const float* cb = ctx + ((size_t)(b*NHEAD + head))*DH*DH + ecol;
    float a0=0,a1=0,a2=0,a3=0;
    #pragma unroll
    for(int d=0; d<DH; ++d){
        float qd = qs[w][head*DH + d];
        float4 c4 = *(const float4*)(cb + d*DH);
        a0 = fmaf(qd, c4.x, a0);
        a1 = fmaf(qd, c4.y, a1);
        a2 = fmaf(qd, c4.z, a2);
        a3 = fmaf(qd, c4.w, a3);
    }
    ushort4 o4; o4.x=f2b(a0); o4.y=f2b(a1); o4.z=f2b(a2); o4.w=f2b(a3);
    *(ushort4*)(att + row*EMBD + lane*4) = o4;
}

__global__ void store_f32(const float* __restrict__ X, float* __restrict__ o, long n4){
    for(long i = (long)blockIdx.x*blockDim.x + threadIdx.x; i < n4;
        i += (long)gridDim.x*blockDim.x)
        *(float4*)(o + i*4) = *(const float4*)(X + i*4);
}

// ---------------- launch ----------------
extern "C" void kernel_launch(void* const* d_in, const int* in_sizes, int n_in,
                              void* d_out, int out_size, void* d_ws, size_t ws_size,
                              hipStream_t stream)
{
    if(n_in != 18) return;

    const float* x     = (const float*)d_in[0];
    const float* noise = (const float*)d_in[1];
    const float* Wproj = (const float*)d_in[2];
    const float* bproj = (const float*)d_in[3];
    const float* ctok  = (const float*)d_in[4];
    const float* ln1s  = (const float*)d_in[5];
    const float* ln1b  = (const float*)d_in[6];
    const float* Wq    = (const float*)d_in[7];
    const float* Wk    = (const float*)d_in[8];
    const float* Wv    = (const float*)d_in[9];
    const float* Wo    = (const float*)d_in[10];
    const float* bo    = (const float*)d_in[11];
    const float* ln2s  = (const float*)d_in[12];
    const float* ln2b  = (const float*)d_in[13];
    const float* W1    = (const float*)d_in[14];
    const float* b1    = (const float*)d_in[15];
    const float* W2    = (const float*)d_in[16];
    const float* b2    = (const float*)d_in[17];

    float* ws   = (float*)d_ws;
    float* bufH = ws;                                    // f32 [NTOK]
    float* big  = ws + (size_t)NTOK;                     // 2*NTOK f32 = 229MB region
    unsigned short* qkvb   = (unsigned short*)big;       // bf16 [BSR][768] (layers)
    float*          dftout = big;                        // f32 [BSR][256] (pre-layer)
    unsigned short* hidb   = (unsigned short*)big;       // bf16 [BSR][1024] (FFN)
    unsigned short* specb  = (unsigned short*)(big + (size_t)NTOK); // bf16 [BSR][128]
    unsigned short* bufYb  = (unsigned short*)(big + 2*(size_t)NTOK); // bf16 [NTOK]
    unsigned short* framesb= bufYb;                      // bf16 [BSR][256] (pre-layer)
    unsigned short* attb   = bufYb;                      // bf16 att out (after y dead)
    float* kmax = (float*)(bufYb + (size_t)NTOK);
    float* ksum = kmax + BB*EMBD;
    float* ctxb = ksum + BB*EMBD;
    float* peb  = ctxb + (size_t)BB*NHEAD*DH*DH;
    unsigned short* twb  = (unsigned short*)(peb + TT*EMBD);   // [256][256]
    unsigned short* Wpb  = twb + 65536;                        // [256][128]
    unsigned short* wbuf = Wpb + 32768;                        // per-layer weights
    const size_t WL = 786432;    // (768+256)*256 + 2*262144
    size_t need_bytes = ((char*)(wbuf + 4*WL)) - (char*)d_ws;
    if(ws_size < need_bytes) return;

    float* out      = (float*)d_out;
    float* o_emb    = out;
    float* o_masked = out + (size_t)NTOK;
    float* o_h      = out + 2*(size_t)NTOK;
    float* o_mask   = out + 3*(size_t)NTOK;

    dim3 blk(256);

    // ---- prep ----
    init_twb<<<256, blk, 0, stream>>>(twb);
    init_pe <<<19,  blk, 0, stream>>>(peb);
    wprep_proj<<<128, blk, 0, stream>>>(Wproj, Wpb);
    for(int l=0;l<NDEPTH;++l){
        unsigned short* wl = wbuf + (size_t)l*WL;
        // QKV fused [768][256]: rows 0..255=Wq, 256..511=Wk, 512..767=Wv
        wprep<<<256,  blk, 0, stream>>>(Wq + (size_t)l*65536,  wl,           256, 256);
        wprep<<<256,  blk, 0, stream>>>(Wk + (size_t)l*65536,  wl + 65536,   256, 256);
        wprep<<<256,  blk, 0, stream>>>(Wv + (size_t)l*65536,  wl + 131072,  256, 256);
        wprep<<<256,  blk, 0, stream>>>(Wo + (size_t)l*65536,  wl + 196608,  256, 256);
        wprep<<<1024, blk, 0, stream>>>(W1 + (size_t)l*262144, wl + 262144,  256, 1024);
        wprep<<<1024, blk, 0, stream>>>(W2 + (size_t)l*262144, wl + 524288,  1024, 256);
    }

    // ---- front end: frames -> DFT GEMM -> |.| -> emb GEMM (fused epilogue) ----
    frames_bf16<<<4096, blk, 0, stream>>>(x, framesb);
    gemm_mfma<0><<<dim3(2,874), blk, 0, stream>>>(framesb, twb, nullptr, dftout,
                                                  BSR, 256, 256);
    combine_bf16<<<4096, blk, 0, stream>>>(dftout, specb);
    gemm_emb<<<dim3(2,874), blk, 0, stream>>>(specb, Wpb, bproj, ctok, peb, noise,
                                              o_emb, o_masked, o_mask, bufH);

    // ---- transformer layers ----
    for(int l=0;l<NDEPTH;++l){
        unsigned short* wl   = wbuf + (size_t)l*WL;
        unsigned short* Wqkv = wl;             // [768][256]
        unsigned short* Wot  = wl + 196608;    // [256][256]
        unsigned short* W1t  = wl + 262144;    // [1024][256]
        unsigned short* W2t  = wl + 524288;    // [256][1024]

        ln_bf16<<<BSR/4, blk, 0, stream>>>(bufH, ln1s + l*EMBD, ln1b + l*EMBD, bufYb);
        gemm_mfma<3><<<dim3(6,874), blk, 0, stream>>>(bufYb, Wqkv, nullptr, qkvb,
                                                      BSR, QKVW, EMBD);
        colstats<<<BB, blk, 0, stream>>>(qkvb, kmax, ksum);
        ctx_kernel<<<BB*NHEAD, blk, 0, stream>>>(qkvb, kmax, ksum, ctxb);
        att_kernel<<<dim3(110, BB), blk, 0, stream>>>(qkvb, ctxb, attb);
        gemm_mfma<1><<<dim3(2,874), blk, 0, stream>>>(attb, Wot, bo + l*EMBD, bufH,
                                                      BSR, EMBD, EMBD);
        ln_bf16<<<BSR/4, blk, 0, stream>>>(bufH, ln2s + l*EMBD, ln2b + l*EMBD, bufYb);
        gemm_mfma<2><<<dim3(8,874), blk, 0, stream>>>(bufYb, W1t, b1 + l*HID, hidb,
                                                      BSR, HID, EMBD);
        gemm_mfma<1><<<dim3(2,874), blk, 0, stream>>>(hidb, W2t, b2 + l*EMBD, bufH,
                                                      BSR, EMBD, HID);
    }
    store_f32<<<4096, blk, 0, stream>>>(bufH, o_h, (long)NTOK/4);
}

// Round 11
// 3534.716 us; speedup vs baseline: 13.0833x; 1.3327x over previous
//
#include <hip/hip_runtime.h>

#define BB    256
#define NCH   23
#define TT    19
#define SS    437          // NCH*TT
#define BSR   111872       // BB*SS
#define EMBD  256
#define NHEAD 8
#define DH    32
#define NFREQ 101
#define NFFT  200
#define HOPSZ 100
#define TSLEN 2000
#define HID   1024
#define NDEPTH 4
#define NTOK  28639232     // BSR*EMBD
#define QKVW  768
#define WL    786432       // bf16 weight elements per layer

typedef __attribute__((ext_vector_type(8))) __bf16 bf16x8;
typedef __attribute__((ext_vector_type(4))) float  f32x4;

__device__ __forceinline__ float gelu_f(float x){
    return 0.5f*x*(1.0f + tanhf(0.7978845608028654f*(x + 0.044715f*x*x*x)));
}
__device__ __forceinline__ unsigned short f2b(float f){   // f32 -> bf16 RNE
    unsigned u = __float_as_uint(f);
    return (unsigned short)((u + 0x7FFFu + ((u >> 16) & 1u)) >> 16);
}
__device__ __forceinline__ float b2f(unsigned short h){
    return __uint_as_float(((unsigned)h) << 16);
}

// XCD-bijective tile swizzle (m204): consecutive logical tiles -> same XCD L2.
__device__ __forceinline__ void swz_tile(int& bx, int& by){
    int nx = gridDim.x, nwg = nx * gridDim.y;
    int lid = blockIdx.y * nx + blockIdx.x;
    int q = nwg >> 3, r = nwg & 7;
    int xcd = lid & 7, off = lid >> 3;
    int wgid = (xcd < r ? xcd*(q+1) : r*(q+1) + (xcd-r)*q) + off;
    bx = wgid % nx; by = wgid / nx;
}

// ---------------- DFT table bf16 [256][256] ----------------
__global__ void init_twb(unsigned short* __restrict__ tw){
    int i = blockIdx.x*256 + threadIdx.x;
    if(i >= 256*256) return;
    int n = i >> 8, k = i & 255;
    float v = 0.f;
    if(k < NFFT){
        if(n <= 100){
            int ph = (n * k) % NFFT;
            v = cosf(6.283185307179586f * (float)ph / (float)NFFT);
        } else if(n >= 128 && n <= 228){
            int ph = ((n - 128) * k) % NFFT;
            v = sinf(6.283185307179586f * (float)ph / (float)NFFT);
        }
    }
    tw[i] = f2b(v);
}

// posenc table f32 [TT][EMBD]
__global__ void init_pe(float* __restrict__ pe){
    int i = blockIdx.x*256 + threadIdx.x;
    if(i >= TT*EMBD) return;
    int t = i / EMBD, e = i % EMBD;
    int j = e >> 1;
    float div = expf((float)(2*j) * (-9.210340371976184f/256.0f));
    float ang = (float)t * div;
    pe[i] = (e & 1) ? cosf(ang) : sinf(ang);
}

// W_proj -> bf16 transposed+padded [256][128]
__global__ void wprep_proj(const float* __restrict__ Wp, unsigned short* __restrict__ Wt){
    int i = blockIdx.x*256 + threadIdx.x;
    if(i >= 256*128) return;
    int e = i >> 7, k = i & 127;
    Wt[i] = f2b(k < NFREQ ? Wp[(size_t)k*EMBD + e] : 0.f);
}

// batched weight prep (all layers in one kernel each)
__global__ void wprep_qkv(const float* __restrict__ Wq, const float* __restrict__ Wk,
                          const float* __restrict__ Wv, unsigned short* __restrict__ wbuf){
    long i = (long)blockIdx.x*256 + threadIdx.x;     // 4*768*256
    if(i >= (long)NDEPTH*QKVW*EMBD) return;
    int l = (int)(i / (QKVW*EMBD));
    int rem = (int)(i % (QKVW*EMBD));
    int n = rem >> 8, k = rem & 255;
    const float* W = (n < 256) ? Wq : (n < 512) ? Wk : Wv;
    wbuf[(size_t)l*WL + rem] = f2b(W[(size_t)l*65536 + (size_t)k*256 + (n & 255)]);
}
__global__ void wprep_wo(const float* __restrict__ Wo, unsigned short* __restrict__ wbuf){
    int i = blockIdx.x*256 + threadIdx.x;            // 4*65536
    if(i >= NDEPTH*65536) return;
    int l = i >> 16, rem = i & 65535;
    int n = rem >> 8, k = rem & 255;
    wbuf[(size_t)l*WL + 196608 + rem] = f2b(Wo[(size_t)l*65536 + (size_t)k*256 + n]);
}
__global__ void wprep_w1(const float* __restrict__ W1, unsigned short* __restrict__ wbuf){
    long i = (long)blockIdx.x*256 + threadIdx.x;     // 4*262144
    if(i >= (long)NDEPTH*262144) return;
    int l = (int)(i >> 18), rem = (int)(i & 262143);
    int n = rem >> 8, k = rem & 255;
    wbuf[(size_t)l*WL + 262144 + rem] = f2b(W1[(size_t)l*262144 + (size_t)k*1024 + n]);
}
__global__ void wprep_w2(const float* __restrict__ W2, unsigned short* __restrict__ wbuf){
    long i = (long)blockIdx.x*256 + threadIdx.x;     // 4*262144
    if(i >= (long)NDEPTH*262144) return;
    int l = (int)(i >> 18), rem = (int)(i & 262143);
    int n = rem >> 10, k = rem & 1023;
    wbuf[(size_t)l*WL + 524288 + rem] = f2b(W2[(size_t)l*262144 + (size_t)k*256 + n]);
}

// frames bf16 [BSR][256]
__global__ void frames_bf16(const float* __restrict__ x, unsigned short* __restrict__ fr){
    for(long i = (long)blockIdx.x*blockDim.x + threadIdx.x; i < (long)BSR*256;
        i += (long)gridDim.x*blockDim.x){
        int  k   = (int)(i & 255);
        long row = i >> 8;
        int  t   = (int)(row % TT);
        long bc  = row / TT;
        float v = (k < NFFT) ? x[bc*(long)TSLEN + (long)t*HOPSZ + k] : 0.f;
        fr[i] = f2b(v);
    }
}

// spec bf16 [BSR][128] from dft f32 [BSR][256]
__global__ void combine_bf16(const float* __restrict__ dft, unsigned short* __restrict__ sp){
    for(long i = (long)blockIdx.x*blockDim.x + threadIdx.x; i < (long)BSR*128;
        i += (long)gridDim.x*blockDim.x){
        int  f   = (int)(i & 127);
        long row = i >> 7;
        float v = 0.f;
        if(f < NFREQ){
            float c = dft[row*256 + f];
            float s = dft[row*256 + 128 + f];
            v = sqrtf(c*c + s*s);
        }
        sp[i] = f2b(v);
    }
}

// ---------------- MFMA bf16 GEMM core (128x128 tile, BK=64, XCD swizzle) -----
// MODE 0: Cf32=acc ; MODE 1: Cf32=Cin+acc+bias ; MODE 2: Cbf16=gelu(acc+bias)
// MODE 3: Cbf16=acc
template<int MODE>
__global__ __launch_bounds__(256) void gemm_mfma(
    const unsigned short* __restrict__ A, const unsigned short* __restrict__ Bt,
    const float* __restrict__ bias, void* __restrict__ Cv,
    const float* __restrict__ Cin, int M, int N, int K)
{
    __shared__ __align__(16) unsigned short As[128*64];
    __shared__ __align__(16) unsigned short Bs[128*64];
    const int tid = threadIdx.x;
    const int w = tid >> 6, l = tid & 63;
    int bx, by; swz_tile(bx, by);
    const int m0 = by * 128, n0 = bx * 128;
    const int wr = w >> 1, wc = w & 1;
    f32x4 acc[4][4];
    #pragma unroll
    for(int i=0;i<4;++i)
        #pragma unroll
        for(int jj=0;jj<4;++jj) acc[i][jj] = (f32x4){0.f,0.f,0.f,0.f};

    const int srow0 = w*32 + (l>>3);
    const int sgrp  = l & 7;

    for(int k0 = 0; k0 < K; k0 += 64){
        #pragma unroll
        for(int it=0; it<4; ++it){
            int row  = srow0 + it*8;
            int colA = ((sgrp ^ (row & 7)) << 3);
            const unsigned short* ga = A  + (size_t)(m0+row)*K + k0 + colA;
            const unsigned short* gb = Bt + (size_t)(n0+row)*K + k0 + colA;
            __builtin_amdgcn_global_load_lds(
                (__attribute__((address_space(1))) void*)ga,
                (__attribute__((address_space(3))) void*)(As + w*2048 + it*512),
                16, 0, 0);
            __builtin_amdgcn_global_load_lds(
                (__attribute__((address_space(1))) void*)gb,
                (__attribute__((address_space(3))) void*)(Bs + w*2048 + it*512),
                16, 0, 0);
        }
        __syncthreads();
        #pragma unroll
        for(int kk=0; kk<2; ++kk){
            bf16x8 af[4], bfr[4];
            #pragma unroll
            for(int mi=0;mi<4;++mi){
                int row = wr*64 + mi*16 + (l & 15);
                int grp = kk*4 + (l >> 4);
                af[mi] = *(const bf16x8*)&As[row*64 + ((grp ^ (row&7))<<3)];
            }
            #pragma unroll
            for(int ni=0;ni<4;++ni){
                int row = wc*64 + ni*16 + (l & 15);
                int grp = kk*4 + (l >> 4);
                bfr[ni] = *(const bf16x8*)&Bs[row*64 + ((grp ^ (row&7))<<3)];
            }
            #pragma unroll
            for(int mi=0;mi<4;++mi)
                #pragma unroll
                for(int ni=0;ni<4;++ni)
                    acc[mi][ni] = __builtin_amdgcn_mfma_f32_16x16x32_bf16(
                        af[mi], bfr[ni], acc[mi][ni], 0, 0, 0);
        }
        __syncthreads();
    }
    const int cn  = l & 15;
    const int cr4 = (l >> 4) * 4;
    if(MODE == 2 || MODE == 3){
        unsigned short* C = (unsigned short*)Cv;
        #pragma unroll
        for(int ni=0;ni<4;++ni){
            int n = n0 + wc*64 + ni*16 + cn;
            float bn = (MODE==2) ? bias[n] : 0.f;
            #pragma unroll
            for(int mi=0;mi<4;++mi){
                int mB = m0 + wr*64 + mi*16 + cr4;
                #pragma unroll
                for(int r=0;r<4;++r){
                    float v = acc[mi][ni][r];
                    C[(size_t)(mB+r)*N + n] = f2b(MODE==2 ? gelu_f(v + bn) : v);
                }
            }
        }
    } else {
        float* C = (float*)Cv;
        #pragma unroll
        for(int ni=0;ni<4;++ni){
            int n = n0 + wc*64 + ni*16 + cn;
            float bn = (MODE==1) ? bias[n] : 0.0f;
            #pragma unroll
            for(int mi=0;mi<4;++mi){
                int mB = m0 + wr*64 + mi*16 + cr4;
                #pragma unroll
                for(int r=0;r<4;++r){
                    size_t off = (size_t)(mB+r)*N + n;
                    if(MODE==0) C[off] = acc[mi][ni][r];
                    else        C[off] = Cin[off] + acc[mi][ni][r] + bn;
                }
            }
        }
    }
}

// ---------------- emb GEMM: spec_b @ Wpb + full fused epilogue ---------------
__global__ __launch_bounds__(256) void gemm_emb(
    const unsigned short* __restrict__ A, const unsigned short* __restrict__ Bt,
    const float* __restrict__ bp, const float* __restrict__ ctok,
    const float* __restrict__ pe, const float* __restrict__ noise,
    float* __restrict__ o_emb, float* __restrict__ o_masked,
    float* __restrict__ o_mask, float* __restrict__ bufH)
{
    const int K = 128, N = 256;
    __shared__ __align__(16) unsigned short As[128*64];
    __shared__ __align__(16) unsigned short Bs[128*64];
    const int tid = threadIdx.x;
    const int w = tid >> 6, l = tid & 63;
    int bx, by; swz_tile(bx, by);
    const int m0 = by * 128, n0 = bx * 128;
    const int wr = w >> 1, wc = w & 1;
    f32x4 acc[4][4];
    #pragma unroll
    for(int i=0;i<4;++i)
        #pragma unroll
        for(int jj=0;jj<4;++jj) acc[i][jj] = (f32x4){0.f,0.f,0.f,0.f};
    const int srow0 = w*32 + (l>>3);
    const int sgrp  = l & 7;
    for(int k0 = 0; k0 < K; k0 += 64){
        #pragma unroll
        for(int it=0; it<4; ++it){
            int row  = srow0 + it*8;
            int colA = ((sgrp ^ (row & 7)) << 3);
            const unsigned short* ga = A  + (size_t)(m0+row)*K + k0 + colA;
            const unsigned short* gb = Bt + (size_t)(n0+row)*K + k0 + colA;
            __builtin_amdgcn_global_load_lds(
                (__attribute__((address_space(1))) void*)ga,
                (__attribute__((address_space(3))) void*)(As + w*2048 + it*512),
                16, 0, 0);
            __builtin_amdgcn_global_load_lds(
                (__attribute__((address_space(1))) void*)gb,
                (__attribute__((address_space(3))) void*)(Bs + w*2048 + it*512),
                16, 0, 0);
        }
        __syncthreads();
        #pragma unroll
        for(int kk=0; kk<2; ++kk){
            bf16x8 af[4], bfr[4];
            #pragma unroll
            for(int mi=0;mi<4;++mi){
                int row = wr*64 + mi*16 + (l & 15);
                int grp = kk*4 + (l >> 4);
                af[mi] = *(const bf16x8*)&As[row*64 + ((grp ^ (row&7))<<3)];
            }
            #pragma unroll
            for(int ni=0;ni<4;++ni){
                int row = wc*64 + ni*16 + (l & 15);
                int grp = kk*4 + (l >> 4);
                bfr[ni] = *(const bf16x8*)&Bs[row*64 + ((grp ^ (row&7))<<3)];
            }
            #pragma unroll
            for(int mi=0;mi<4;++mi)
                #pragma unroll
                for(int ni=0;ni<4;++ni)
                    acc[mi][ni] = __builtin_amdgcn_mfma_f32_16x16x32_bf16(
                        af[mi], bfr[ni], acc[mi][ni], 0, 0, 0);
        }
        __syncthreads();
    }
    const int cn  = l & 15;
    const int cr4 = (l >> 4) * 4;
    #pragma unroll
    for(int ni=0;ni<4;++ni){
        int n = n0 + wc*64 + ni*16 + cn;
        float bn = bp[n];
        #pragma unroll
        for(int mi=0;mi<4;++mi){
            int mB = m0 + wr*64 + mi*16 + cr4;
            #pragma unroll
            for(int r=0;r<4;++r){
                int m = mB + r;
                int t = m % TT;
                int c = (m / TT) % NCH;
                size_t off = (size_t)m*EMBD + n;
                float v = acc[mi][ni][r] + bn + ctok[c*EMBD + n] + pe[t*EMBD + n];
                o_emb[off] = v;
                float mn = noise[off];
                bool  msk = mn < 0.9f;
                float md = msk ? 0.f : v;
                bufH[off]     = md;
                o_masked[off] = md;
                o_mask[off]   = msk ? 1.f : 0.f;
            }
        }
    }
}

// ---------------- layernorm (wave per row) -> bf16 out ----------------
__global__ __launch_bounds__(256) void ln_bf16(const float* __restrict__ X,
    const float* __restrict__ s, const float* __restrict__ b,
    unsigned short* __restrict__ Y)
{
    int w = threadIdx.x >> 6, lane = threadIdx.x & 63;
    long row = (long)blockIdx.x*4 + w;
    const float* xr = X + row*EMBD;
    float4 v = *(const float4*)(xr + lane*4);
    float sum = v.x + v.y + v.z + v.w;
    #pragma unroll
    for(int o=32;o>0;o>>=1) sum += __shfl_xor(sum, o, 64);
    float mu = sum * (1.0f/256.0f);
    float dx = v.x-mu, dy = v.y-mu, dz = v.z-mu, dw = v.w-mu;
    float vs = dx*dx + dy*dy + dz*dz + dw*dw;
    #pragma unroll
    for(int o=32;o>0;o>>=1) vs += __shfl_xor(vs, o, 64);
    float rstd = rsqrtf(vs*(1.0f/256.0f) + 1e-5f);
    float4 s4 = *(const float4*)(s + lane*4);
    float4 b4 = *(const float4*)(b + lane*4);
    ushort4 o4;
    o4.x = f2b(dx*rstd*s4.x + b4.x);
    o4.y = f2b(dy*rstd*s4.y + b4.y);
    o4.z = f2b(dz*rstd*s4.z + b4.z);
    o4.w = f2b(dw*rstd*s4.w + b4.w);
    *(ushort4*)(Y + row*EMBD + lane*4) = o4;
}

// ---------------- parallel k-softmax column stats ----------------
// grid (BB, 8); block = 32 cols x 8 row-groups; LDS log-sum-exp merge.
__global__ __launch_bounds__(256) void colstats(const unsigned short* __restrict__ qkvb,
                         float* __restrict__ kmax, float* __restrict__ ksum)
{
    __shared__ float sm[8][32], ss[8][32];
    int b = blockIdx.x;
    int c = blockIdx.y*32 + (threadIdx.x & 31);
    int g = threadIdx.x >> 5;
    const unsigned short* p = qkvb + (size_t)b*SS*QKVW + 256 + c;
    float m = -1e30f, s = 0.f;
    for(int n = g; n < SS; n += 8){
        float xv = b2f(p[(size_t)n*QKVW]);
        if(xv > m){ s = s*expf(m-xv) + 1.f; m = xv; }
        else      { s += expf(xv-m); }
    }
    sm[g][threadIdx.x & 31] = m;
    ss[g][threadIdx.x & 31] = s;
    __syncthreads();
    if(g == 0){
        int lc = threadIdx.x & 31;
        float M = m, S = s;
        #pragma unroll
        for(int o = 1; o < 8; ++o){
            float m2 = sm[o][lc], s2 = ss[o][lc];
            if(m2 > M){ S = S*expf(M-m2) + s2; M = m2; }
            else      { S += s2*expf(m2-M); }
        }
        kmax[b*EMBD + c] = M;
        ksum[b*EMBD + c] = S;
    }
}

// ---------------- ctx[b,h,d,e] = sum_n softmax_S(k)[n,d] * v[n,e] ------------
__global__ __launch_bounds__(256) void ctx_kernel(const unsigned short* __restrict__ qkvb,
    const float* __restrict__ kmax, const float* __restrict__ ksum,
    float* __restrict__ ctx)
{
    __shared__ float kt[16][DH], vt[16][DH];
    int bh = blockIdx.x; int b = bh >> 3, h = bh & 7;
    int tid = threadIdx.x;
    int d = tid >> 3, e4 = (tid & 7) * 4;
    float km = kmax[b*EMBD + h*DH + d];
    float a0=0,a1=0,a2=0,a3=0;
    for(int n0=0;n0<SS;n0+=16){
        __syncthreads();
        #pragma unroll
        for(int i=0;i<2;++i){
            int e = tid + i*256;
            int nn = e >> 5, dd = e & 31;
            int n = n0 + nn;
            float kv, vv;
            if(n < SS){
                size_t off = ((size_t)(b*SS+n))*QKVW + h*DH + dd;
                kv = b2f(qkvb[off + 256]);
                vv = b2f(qkvb[off + 512]);
            } else { kv = -1e30f; vv = 0.f; }
            kt[nn][dd] = kv; vt[nn][dd] = vv;
        }
        __syncthreads();
        #pragma unroll
        for(int nn=0;nn<16;++nn){
            float ke = expf(kt[nn][d] - km);
            a0 = fmaf(ke, vt[nn][e4+0], a0);
            a1 = fmaf(ke, vt[nn][e4+1], a1);
            a2 = fmaf(ke, vt[nn][e4+2], a2);
            a3 = fmaf(ke, vt[nn][e4+3], a3);
        }
    }
    float inv = 1.0f / ksum[b*EMBD + h*DH + d];
    float* op = ctx + ((size_t)bh*DH + d)*DH + e4;
    op[0]=a0*inv; op[1]=a1*inv; op[2]=a2*inv; op[3]=a3*inv;
}

// ---------------- per-token q-softmax + att = q @ ctx -> bf16 ----------------
__global__ __launch_bounds__(256) void att_kernel(const unsigned short* __restrict__ qkvb,
    const float* __restrict__ ctx, unsigned short* __restrict__ att)
{
    __shared__ float qs[4][EMBD];
    int w = threadIdx.x >> 6, lane = threadIdx.x & 63;
    int b = blockIdx.y;
    int s = blockIdx.x*4 + w;
    if(s >= SS) return;
    long row = (long)b*SS + s;
    ushort4 qu = *(const ushort4*)(qkvb + (size_t)row*QKVW + lane*4);
    float4 q4 = make_float4(b2f(qu.x), b2f(qu.y), b2f(qu.z), b2f(qu.w));
    float m = fmaxf(fmaxf(q4.x,q4.y), fmaxf(q4.z,q4.w));
    #pragma unroll
    for(int o=1;o<8;o<<=1) m = fmaxf(m, __shfl_xor(m, o, 64));
    float e0 = expf(q4.x-m), e1 = expf(q4.y-m), e2 = expf(q4.z-m), e3 = expf(q4.w-m);
    float ssum = e0+e1+e2+e3;
    #pragma unroll
    for(int o=1;o<8;o<<=1) ssum += __shfl_xor(ssum, o, 64);
    float sc = 0.17677669529663687f / ssum;
    *(float4*)&qs[w][lane*4] = make_float4(e0*sc, e1*sc, e2*sc, e3*sc);
    int head = lane >> 3;
    int ecol = (lane & 7) * 4;
    const float* cb = ctx + ((size_t)(b*NHEAD + head))*DH*DH + ecol;
    float a0=0,a1=0,a2=0,a3=0;
    #pragma unroll
    for(int d=0; d<DH; ++d){
        float qd = qs[w][head*DH + d];
        float4 c4 = *(const float4*)(cb + d*DH);
        a0 = fmaf(qd, c4.x, a0);
        a1 = fmaf(qd, c4.y, a1);
        a2 = fmaf(qd, c4.z, a2);
        a3 = fmaf(qd, c4.w, a3);
    }
    ushort4 o4; o4.x=f2b(a0); o4.y=f2b(a1); o4.z=f2b(a2); o4.w=f2b(a3);
    *(ushort4*)(att + row*EMBD + lane*4) = o4;
}

// ---------------- launch ----------------
extern "C" void kernel_launch(void* const* d_in, const int* in_sizes, int n_in,
                              void* d_out, int out_size, void* d_ws, size_t ws_size,
                              hipStream_t stream)
{
    if(n_in != 18) return;

    const float* x     = (const float*)d_in[0];
    const float* noise = (const float*)d_in[1];
    const float* Wproj = (const float*)d_in[2];
    const float* bproj = (const float*)d_in[3];
    const float* ctok  = (const float*)d_in[4];
    const float* ln1s  = (const float*)d_in[5];
    const float* ln1b  = (const float*)d_in[6];
    const float* Wq    = (const float*)d_in[7];
    const float* Wk    = (const float*)d_in[8];
    const float* Wv    = (const float*)d_in[9];
    const float* Wo    = (const float*)d_in[10];
    const float* bo    = (const float*)d_in[11];
    const float* ln2s  = (const float*)d_in[12];
    const float* ln2b  = (const float*)d_in[13];
    const float* W1    = (const float*)d_in[14];
    const float* b1    = (const float*)d_in[15];
    const float* W2    = (const float*)d_in[16];
    const float* b2    = (const float*)d_in[17];

    float* ws   = (float*)d_ws;
    float* bufH = ws;                                    // f32 [NTOK]
    float* big  = ws + (size_t)NTOK;                     // 2*NTOK f32 region
    unsigned short* qkvb   = (unsigned short*)big;       // bf16 [BSR][768]
    float*          dftout = big;                        // f32 [BSR][256] (pre-layer)
    unsigned short* hidb   = (unsigned short*)big;       // bf16 [BSR][1024] (FFN)
    unsigned short* specb  = (unsigned short*)(big + (size_t)NTOK); // bf16 [BSR][128]
    unsigned short* bufYb  = (unsigned short*)(big + 2*(size_t)NTOK); // bf16 [NTOK]
    unsigned short* framesb= bufYb;                      // bf16 [BSR][256] (pre-layer)
    unsigned short* attb   = bufYb;                      // bf16 att out
    float* kmax = (float*)(bufYb + (size_t)NTOK);
    float* ksum = kmax + BB*EMBD;
    float* ctxb = ksum + BB*EMBD;
    float* peb  = ctxb + (size_t)BB*NHEAD*DH*DH;
    unsigned short* twb  = (unsigned short*)(peb + TT*EMBD);   // [256][256]
    unsigned short* Wpb  = twb + 65536;                        // [256][128]
    unsigned short* wbuf = Wpb + 32768;                        // per-layer weights
    size_t need_bytes = ((char*)(wbuf + 4*(size_t)WL)) - (char*)d_ws;
    if(ws_size < need_bytes) return;

    float* out      = (float*)d_out;
    float* o_emb    = out;
    float* o_masked = out + (size_t)NTOK;
    float* o_h      = out + 2*(size_t)NTOK;
    float* o_mask   = out + 3*(size_t)NTOK;

    dim3 blk(256);

    // ---- prep ----
    init_twb<<<256, blk, 0, stream>>>(twb);
    init_pe <<<19,  blk, 0, stream>>>(peb);
    wprep_proj<<<128, blk, 0, stream>>>(Wproj, Wpb);
    wprep_qkv<<<3072, blk, 0, stream>>>(Wq, Wk, Wv, wbuf);
    wprep_wo <<<1024, blk, 0, stream>>>(Wo, wbuf);
    wprep_w1 <<<4096, blk, 0, stream>>>(W1, wbuf);
    wprep_w2 <<<4096, blk, 0, stream>>>(W2, wbuf);

    // ---- front end ----
    frames_bf16<<<4096, blk, 0, stream>>>(x, framesb);
    gemm_mfma<0><<<dim3(2,874), blk, 0, stream>>>(framesb, twb, nullptr, dftout,
                                                  nullptr, BSR, 256, 256);
    combine_bf16<<<4096, blk, 0, stream>>>(dftout, specb);
    gemm_emb<<<dim3(2,874), blk, 0, stream>>>(specb, Wpb, bproj, ctok, peb, noise,
                                              o_emb, o_masked, o_mask, bufH);

    // ---- transformer layers ----
    for(int l=0;l<NDEPTH;++l){
        unsigned short* wl   = wbuf + (size_t)l*WL;
        unsigned short* Wqkv = wl;             // [768][256]
        unsigned short* Wot  = wl + 196608;    // [256][256]
        unsigned short* W1t  = wl + 262144;    // [1024][256]
        unsigned short* W2t  = wl + 524288;    // [256][1024]

        ln_bf16<<<BSR/4, blk, 0, stream>>>(bufH, ln1s + l*EMBD, ln1b + l*EMBD, bufYb);
        gemm_mfma<3><<<dim3(6,874), blk, 0, stream>>>(bufYb, Wqkv, nullptr, qkvb,
                                                      nullptr, BSR, QKVW, EMBD);
        colstats<<<dim3(BB,8), blk, 0, stream>>>(qkvb, kmax, ksum);
        ctx_kernel<<<BB*NHEAD, blk, 0, stream>>>(qkvb, kmax, ksum, ctxb);
        att_kernel<<<dim3(110, BB), blk, 0, stream>>>(qkvb, ctxb, attb);
        gemm_mfma<1><<<dim3(2,874), blk, 0, stream>>>(attb, Wot, bo + l*EMBD, bufH,
                                                      bufH, BSR, EMBD, EMBD);
        ln_bf16<<<BSR/4, blk, 0, stream>>>(bufH, ln2s + l*EMBD, ln2b + l*EMBD, bufYb);
        gemm_mfma<2><<<dim3(8,874), blk, 0, stream>>>(bufYb, W1t, b1 + l*HID, hidb,
                                                      nullptr, BSR, HID, EMBD);
        // last layer writes o_h directly (residual read from bufH)
        float* cOut = (l == NDEPTH-1) ? o_h : bufH;
        gemm_mfma<1><<<dim3(2,874), blk, 0, stream>>>(hidb, W2t, b2 + l*EMBD, cOut,
                                                      bufH, BSR, EMBD, HID);
    }
}

// Round 12
// 3304.815 us; speedup vs baseline: 13.9934x; 1.0696x over previous
//
#include <hip/hip_runtime.h>

#define BB    256
#define NCH   23
#define TT    19
#define SS    437          // NCH*TT
#define BSR   111872       // BB*SS
#define EMBD  256
#define NHEAD 8
#define DH    32
#define NFREQ 101
#define NFFT  200
#define HOPSZ 100
#define TSLEN 2000
#define HID   1024
#define NDEPTH 4
#define NTOK  28639232     // BSR*EMBD
#define QKVW  768
#define WL    786432       // bf16 weight elements per layer

typedef __attribute__((ext_vector_type(8))) __bf16 bf16x8;
typedef __attribute__((ext_vector_type(4))) float  f32x4;

__device__ __forceinline__ float gelu_f(float x){
    return 0.5f*x*(1.0f + tanhf(0.7978845608028654f*(x + 0.044715f*x*x*x)));
}
__device__ __forceinline__ unsigned short f2b(float f){   // f32 -> bf16 RNE
    unsigned u = __float_as_uint(f);
    return (unsigned short)((u + 0x7FFFu + ((u >> 16) & 1u)) >> 16);
}
__device__ __forceinline__ float b2f(unsigned short h){
    return __uint_as_float(((unsigned)h) << 16);
}

// XCD-bijective tile swizzle (m204): consecutive logical tiles -> same XCD L2.
__device__ __forceinline__ void swz_tile(int& bx, int& by){
    int nx = gridDim.x, nwg = nx * gridDim.y;
    int lid = blockIdx.y * nx + blockIdx.x;
    int q = nwg >> 3, r = nwg & 7;
    int xcd = lid & 7, off = lid >> 3;
    int wgid = (xcd < r ? xcd*(q+1) : r*(q+1) + (xcd-r)*q) + off;
    bx = wgid % nx; by = wgid / nx;
}

// ---------------- DFT table bf16 [256][256], INTERLEAVED rows ----------------
// row 2f = cos_f, row 2f+1 = sin_f (f<101); rows >=202 zero. col k<200 else 0.
__global__ void init_twb(unsigned short* __restrict__ tw){
    int i = blockIdx.x*256 + threadIdx.x;
    if(i >= 256*256) return;
    int n = i >> 8, k = i & 255;
    float v = 0.f;
    if(k < NFFT && n < 2*NFREQ){
        int f = n >> 1;
        int ph = (f * k) % NFFT;
        float ang = 6.283185307179586f * (float)ph / (float)NFFT;
        v = (n & 1) ? sinf(ang) : cosf(ang);
    }
    tw[i] = f2b(v);
}

// posenc table f32 [TT][EMBD]
__global__ void init_pe(float* __restrict__ pe){
    int i = blockIdx.x*256 + threadIdx.x;
    if(i >= TT*EMBD) return;
    int t = i / EMBD, e = i % EMBD;
    int j = e >> 1;
    float div = expf((float)(2*j) * (-9.210340371976184f/256.0f));
    float ang = (float)t * div;
    pe[i] = (e & 1) ? cosf(ang) : sinf(ang);
}

// W_proj -> bf16 transposed+padded [256][128]
__global__ void wprep_proj(const float* __restrict__ Wp, unsigned short* __restrict__ Wt){
    int i = blockIdx.x*256 + threadIdx.x;
    if(i >= 256*128) return;
    int e = i >> 7, k = i & 127;
    Wt[i] = f2b(k < NFREQ ? Wp[(size_t)k*EMBD + e] : 0.f);
}

// batched weight prep
__global__ void wprep_qkv(const float* __restrict__ Wq, const float* __restrict__ Wk,
                          const float* __restrict__ Wv, unsigned short* __restrict__ wbuf){
    long i = (long)blockIdx.x*256 + threadIdx.x;
    if(i >= (long)NDEPTH*QKVW*EMBD) return;
    int l = (int)(i / (QKVW*EMBD));
    int rem = (int)(i % (QKVW*EMBD));
    int n = rem >> 8, k = rem & 255;
    const float* W = (n < 256) ? Wq : (n < 512) ? Wk : Wv;
    wbuf[(size_t)l*WL + rem] = f2b(W[(size_t)l*65536 + (size_t)k*256 + (n & 255)]);
}
__global__ void wprep_wo(const float* __restrict__ Wo, unsigned short* __restrict__ wbuf){
    int i = blockIdx.x*256 + threadIdx.x;
    if(i >= NDEPTH*65536) return;
    int l = i >> 16, rem = i & 65535;
    int n = rem >> 8, k = rem & 255;
    wbuf[(size_t)l*WL + 196608 + rem] = f2b(Wo[(size_t)l*65536 + (size_t)k*256 + n]);
}
__global__ void wprep_w1(const float* __restrict__ W1, unsigned short* __restrict__ wbuf){
    long i = (long)blockIdx.x*256 + threadIdx.x;
    if(i >= (long)NDEPTH*262144) return;
    int l = (int)(i >> 18), rem = (int)(i & 262143);
    int n = rem >> 8, k = rem & 255;
    wbuf[(size_t)l*WL + 262144 + rem] = f2b(W1[(size_t)l*262144 + (size_t)k*1024 + n]);
}
__global__ void wprep_w2(const float* __restrict__ W2, unsigned short* __restrict__ wbuf){
    long i = (long)blockIdx.x*256 + threadIdx.x;
    if(i >= (long)NDEPTH*262144) return;
    int l = (int)(i >> 18), rem = (int)(i & 262143);
    int n = rem >> 10, k = rem & 1023;
    wbuf[(size_t)l*WL + 524288 + rem] = f2b(W2[(size_t)l*262144 + (size_t)k*256 + n]);
}

// frames bf16 [BSR][256]
__global__ void frames_bf16(const float* __restrict__ x, unsigned short* __restrict__ fr){
    for(long i = (long)blockIdx.x*blockDim.x + threadIdx.x; i < (long)BSR*256;
        i += (long)gridDim.x*blockDim.x){
        int  k   = (int)(i & 255);
        long row = i >> 8;
        int  t   = (int)(row % TT);
        long bc  = row / TT;
        float v = (k < NFFT) ? x[bc*(long)TSLEN + (long)t*HOPSZ + k] : 0.f;
        fr[i] = f2b(v);
    }
}

// =============== shared GEMM core macro-ish (staging + MFMA loop) ============
#define GEMM_CORE(A_, B_, K_) \
    f32x4 acc[4][4]; \
    _Pragma("unroll") \
    for(int i=0;i<4;++i) \
        _Pragma("unroll") \
        for(int jj=0;jj<4;++jj) acc[i][jj] = (f32x4){0.f,0.f,0.f,0.f}; \
    const int srow0 = w*32 + (l>>3); \
    const int sgrp  = l & 7; \
    for(int k0 = 0; k0 < (K_); k0 += 64){ \
        _Pragma("unroll") \
        for(int it=0; it<4; ++it){ \
            int row  = srow0 + it*8; \
            int colA = ((sgrp ^ (row & 7)) << 3); \
            const unsigned short* ga = (A_) + (size_t)(m0+row)*(K_) + k0 + colA; \
            const unsigned short* gb = (B_) + (size_t)(n0+row)*(K_) + k0 + colA; \
            __builtin_amdgcn_global_load_lds( \
                (__attribute__((address_space(1))) void*)ga, \
                (__attribute__((address_space(3))) void*)(As + w*2048 + it*512), \
                16, 0, 0); \
            __builtin_amdgcn_global_load_lds( \
                (__attribute__((address_space(1))) void*)gb, \
                (__attribute__((address_space(3))) void*)(Bs + w*2048 + it*512), \
                16, 0, 0); \
        } \
        __syncthreads(); \
        _Pragma("unroll") \
        for(int kk=0; kk<2; ++kk){ \
            bf16x8 af[4], bfr[4]; \
            _Pragma("unroll") \
            for(int mi=0;mi<4;++mi){ \
                int row = wr*64 + mi*16 + (l & 15); \
                int grp = kk*4 + (l >> 4); \
                af[mi] = *(const bf16x8*)&As[row*64 + ((grp ^ (row&7))<<3)]; \
            } \
            _Pragma("unroll") \
            for(int ni=0;ni<4;++ni){ \
                int row = wc*64 + ni*16 + (l & 15); \
                int grp = kk*4 + (l >> 4); \
                bfr[ni] = *(const bf16x8*)&Bs[row*64 + ((grp ^ (row&7))<<3)]; \
            } \
            _Pragma("unroll") \
            for(int mi=0;mi<4;++mi) \
                _Pragma("unroll") \
                for(int ni=0;ni<4;++ni) \
                    acc[mi][ni] = __builtin_amdgcn_mfma_f32_16x16x32_bf16( \
                        af[mi], bfr[ni], acc[mi][ni], 0, 0, 0); \
        } \
        __syncthreads(); \
    }

// ---------------- general MFMA GEMM ----------------
// MODE 1: Cbf16 = b2f(Cin_bf16) + acc + bias
// MODE 2: Cbf16 = gelu(acc + bias)
// MODE 3: Cbf16 = acc
// MODE 4: Cf32  = b2f(Cin_bf16) + acc + bias   (final o_h)
template<int MODE>
__global__ __launch_bounds__(256) void gemm_mfma(
    const unsigned short* __restrict__ A, const unsigned short* __restrict__ Bt,
    const float* __restrict__ bias, void* __restrict__ Cv,
    const unsigned short* __restrict__ Cin, int M, int N, int K)
{
    __shared__ __align__(16) unsigned short As[128*64];
    __shared__ __align__(16) unsigned short Bs[128*64];
    const int tid = threadIdx.x;
    const int w = tid >> 6, l = tid & 63;
    int bx, by; swz_tile(bx, by);
    const int m0 = by * 128, n0 = bx * 128;
    const int wr = w >> 1, wc = w & 1;
    GEMM_CORE(A, Bt, K)
    const int cn  = l & 15;
    const int cr4 = (l >> 4) * 4;
    #pragma unroll
    for(int ni=0;ni<4;++ni){
        int n = n0 + wc*64 + ni*16 + cn;
        float bn = (MODE==1 || MODE==2 || MODE==4) ? bias[n] : 0.f;
        #pragma unroll
        for(int mi=0;mi<4;++mi){
            int mB = m0 + wr*64 + mi*16 + cr4;
            #pragma unroll
            for(int r=0;r<4;++r){
                size_t off = (size_t)(mB+r)*N + n;
                float v = acc[mi][ni][r];
                if(MODE == 1){
                    ((unsigned short*)Cv)[off] = f2b(b2f(Cin[off]) + v + bn);
                } else if(MODE == 2){
                    ((unsigned short*)Cv)[off] = f2b(gelu_f(v + bn));
                } else if(MODE == 3){
                    ((unsigned short*)Cv)[off] = f2b(v);
                } else {
                    ((float*)Cv)[off] = b2f(Cin[off]) + v + bn;
                }
            }
        }
    }
}

// ---------------- DFT GEMM with fused |.| epilogue -> spec bf16 [BSR][128] ---
__global__ __launch_bounds__(256) void gemm_dft(
    const unsigned short* __restrict__ A, const unsigned short* __restrict__ Bt,
    unsigned short* __restrict__ spec)
{
    const int K = 256;
    __shared__ __align__(16) unsigned short As[128*64];
    __shared__ __align__(16) unsigned short Bs[128*64];
    const int tid = threadIdx.x;
    const int w = tid >> 6, l = tid & 63;
    int bx, by; swz_tile(bx, by);
    const int m0 = by * 128, n0 = bx * 128;
    const int wr = w >> 1, wc = w & 1;
    GEMM_CORE(A, Bt, K)
    const int cn  = l & 15;
    const int cr4 = (l >> 4) * 4;
    #pragma unroll
    for(int ni=0;ni<4;++ni){
        int n = n0 + wc*64 + ni*16 + cn;
        #pragma unroll
        for(int mi=0;mi<4;++mi){
            int mB = m0 + wr*64 + mi*16 + cr4;
            #pragma unroll
            for(int r=0;r<4;++r){
                float own = acc[mi][ni][r];
                float par = __shfl_xor(own, 1, 64);   // partner col n^1
                if(!(cn & 1)){
                    float sv = sqrtf(own*own + par*par);   // cos=own, sin=par
                    spec[(size_t)(mB+r)*128 + (n >> 1)] = f2b(sv);
                }
            }
        }
    }
}

// ---------------- emb GEMM: spec_b @ Wpb + full fused epilogue ---------------
__global__ __launch_bounds__(256) void gemm_emb(
    const unsigned short* __restrict__ A, const unsigned short* __restrict__ Bt,
    const float* __restrict__ bp, const float* __restrict__ ctok,
    const float* __restrict__ pe, const float* __restrict__ noise,
    float* __restrict__ o_emb, float* __restrict__ o_masked,
    float* __restrict__ o_mask, unsigned short* __restrict__ bufH)
{
    const int K = 128, N = 256;
    __shared__ __align__(16) unsigned short As[128*64];
    __shared__ __align__(16) unsigned short Bs[128*64];
    const int tid = threadIdx.x;
    const int w = tid >> 6, l = tid & 63;
    int bx, by; swz_tile(bx, by);
    const int m0 = by * 128, n0 = bx * 128;
    const int wr = w >> 1, wc = w & 1;
    GEMM_CORE(A, Bt, K)
    const int cn  = l & 15;
    const int cr4 = (l >> 4) * 4;
    #pragma unroll
    for(int ni=0;ni<4;++ni){
        int n = n0 + wc*64 + ni*16 + cn;
        float bn = bp[n];
        #pragma unroll
        for(int mi=0;mi<4;++mi){
            int mB = m0 + wr*64 + mi*16 + cr4;
            #pragma unroll
            for(int r=0;r<4;++r){
                int m = mB + r;
                int t = m % TT;
                int c = (m / TT) % NCH;
                size_t off = (size_t)m*EMBD + n;
                float v = acc[mi][ni][r] + bn + ctok[c*EMBD + n] + pe[t*EMBD + n];
                o_emb[off] = v;
                float mn = noise[off];
                bool  msk = mn < 0.9f;
                float md = msk ? 0.f : v;
                bufH[off]     = f2b(md);
                o_masked[off] = md;
                o_mask[off]   = msk ? 1.f : 0.f;
            }
        }
    }
}

// ---------------- layernorm (wave per row), bf16 in -> bf16 out --------------
__global__ __launch_bounds__(256) void ln_bf16(const unsigned short* __restrict__ X,
    const float* __restrict__ s, const float* __restrict__ b,
    unsigned short* __restrict__ Y)
{
    int w = threadIdx.x >> 6, lane = threadIdx.x & 63;
    long row = (long)blockIdx.x*4 + w;
    ushort4 u = *(const ushort4*)(X + row*EMBD + lane*4);
    float x0 = b2f(u.x), x1 = b2f(u.y), x2 = b2f(u.z), x3 = b2f(u.w);
    float sum = x0 + x1 + x2 + x3;
    #pragma unroll
    for(int o=32;o>0;o>>=1) sum += __shfl_xor(sum, o, 64);
    float mu = sum * (1.0f/256.0f);
    float dx = x0-mu, dy = x1-mu, dz = x2-mu, dw = x3-mu;
    float vs = dx*dx + dy*dy + dz*dz + dw*dw;
    #pragma unroll
    for(int o=32;o>0;o>>=1) vs += __shfl_xor(vs, o, 64);
    float rstd = rsqrtf(vs*(1.0f/256.0f) + 1e-5f);
    float4 s4 = *(const float4*)(s + lane*4);
    float4 b4 = *(const float4*)(b + lane*4);
    ushort4 o4;
    o4.x = f2b(dx*rstd*s4.x + b4.x);
    o4.y = f2b(dy*rstd*s4.y + b4.y);
    o4.z = f2b(dz*rstd*s4.z + b4.z);
    o4.w = f2b(dw*rstd*s4.w + b4.w);
    *(ushort4*)(Y + row*EMBD + lane*4) = o4;
}

// ---------------- ctx with fused k-softmax stats -----------------------------
// block (b,h). Phase A: per-d online max/sum over n (8-way split + LSE merge).
// Phase B: ctx[d][e] = sum_n exp(k[n,d]-km)*v[n,e] / ksum.
__global__ __launch_bounds__(256) void ctx_kernel(const unsigned short* __restrict__ qkvb,
    float* __restrict__ ctx)
{
    __shared__ float kt[16][DH], vt[16][DH];
    __shared__ float sm[8][32], ss[8][32];
    __shared__ float kmsL[32], kinvL[32];
    int bh = blockIdx.x; int b = bh >> 3, h = bh & 7;
    int tid = threadIdx.x;

    // ---- phase A: column stats ----
    {
        int d = tid & 31, g = tid >> 5;
        const unsigned short* p = qkvb + (size_t)b*SS*QKVW + 256 + h*DH + d;
        float m = -1e30f, s = 0.f;
        for(int n = g; n < SS; n += 8){
            float xv = b2f(p[(size_t)n*QKVW]);
            if(xv > m){ s = s*expf(m-xv) + 1.f; m = xv; }
            else      { s += expf(xv-m); }
        }
        sm[g][d] = m; ss[g][d] = s;
    }
    __syncthreads();
    if(tid < 32){
        float M = sm[0][tid], S = ss[0][tid];
        #pragma unroll
        for(int o = 1; o < 8; ++o){
            float m2 = sm[o][tid], s2 = ss[o][tid];
            if(m2 > M){ S = S*expf(M-m2) + s2; M = m2; }
            else      { S += s2*expf(m2-M); }
        }
        kmsL[tid] = M; kinvL[tid] = 1.0f / S;
    }
    __syncthreads();

    // ---- phase B: weighted accumulation ----
    int d = tid >> 3, e4 = (tid & 7) * 4;
    float km = kmsL[d];
    float a0=0,a1=0,a2=0,a3=0;
    for(int n0=0;n0<SS;n0+=16){
        __syncthreads();
        #pragma unroll
        for(int i=0;i<2;++i){
            int e = tid + i*256;
            int nn = e >> 5, dd = e & 31;
            int n = n0 + nn;
            float kv, vv;
            if(n < SS){
                size_t off = ((size_t)(b*SS+n))*QKVW + h*DH + dd;
                kv = b2f(qkvb[off + 256]);
                vv = b2f(qkvb[off + 512]);
            } else { kv = -1e30f; vv = 0.f; }
            kt[nn][dd] = kv; vt[nn][dd] = vv;
        }
        __syncthreads();
        #pragma unroll
        for(int nn=0;nn<16;++nn){
            float ke = expf(kt[nn][d] - km);
            a0 = fmaf(ke, vt[nn][e4+0], a0);
            a1 = fmaf(ke, vt[nn][e4+1], a1);
            a2 = fmaf(ke, vt[nn][e4+2], a2);
            a3 = fmaf(ke, vt[nn][e4+3], a3);
        }
    }
    float inv = kinvL[d];
    float* op = ctx + ((size_t)bh*DH + d)*DH + e4;
    op[0]=a0*inv; op[1]=a1*inv; op[2]=a2*inv; op[3]=a3*inv;
}

// ---------------- per-token q-softmax + att = q @ ctx -> bf16 ----------------
__global__ __launch_bounds__(256) void att_kernel(const unsigned short* __restrict__ qkvb,
    const float* __restrict__ ctx, unsigned short* __restrict__ att)
{
    __shared__ float qs[4][EMBD];
    int w = threadIdx.x >> 6, lane = threadIdx.x & 63;
    int b = blockIdx.y;
    int s = blockIdx.x*4 + w;
    if(s >= SS) return;
    long row = (long)b*SS + s;
    ushort4 qu = *(const ushort4*)(qkvb + (size_t)row*QKVW + lane*4);
    float4 q4 = make_float4(b2f(qu.x), b2f(qu.y), b2f(qu.z), b2f(qu.w));
    float m = fmaxf(fmaxf(q4.x,q4.y), fmaxf(q4.z,q4.w));
    #pragma unroll
    for(int o=1;o<8;o<<=1) m = fmaxf(m, __shfl_xor(m, o, 64));
    float e0 = expf(q4.x-m), e1 = expf(q4.y-m), e2 = expf(q4.z-m), e3 = expf(q4.w-m);
    float ssum = e0+e1+e2+e3;
    #pragma unroll
    for(int o=1;o<8;o<<=1) ssum += __shfl_xor(ssum, o, 64);
    float sc = 0.17677669529663687f / ssum;
    *(float4*)&qs[w][lane*4] = make_float4(e0*sc, e1*sc, e2*sc, e3*sc);
    int head = lane >> 3;
    int ecol = (lane & 7) * 4;
    const float* cb = ctx + ((size_t)(b*NHEAD + head))*DH*DH + ecol;
    float a0=0,a1=0,a2=0,a3=0;
    #pragma unroll
    for(int d=0; d<DH; ++d){
        float qd = qs[w][head*DH + d];
        float4 c4 = *(const float4*)(cb + d*DH);
        a0 = fmaf(qd, c4.x, a0);
        a1 = fmaf(qd, c4.y, a1);
        a2 = fmaf(qd, c4.z, a2);
        a3 = fmaf(qd, c4.w, a3);
    }
    ushort4 o4; o4.x=f2b(a0); o4.y=f2b(a1); o4.z=f2b(a2); o4.w=f2b(a3);
    *(ushort4*)(att + row*EMBD + lane*4) = o4;
}

// ---------------- launch ----------------
extern "C" void kernel_launch(void* const* d_in, const int* in_sizes, int n_in,
                              void* d_out, int out_size, void* d_ws, size_t ws_size,
                              hipStream_t stream)
{
    if(n_in != 18) return;

    const float* x     = (const float*)d_in[0];
    const float* noise = (const float*)d_in[1];
    const float* Wproj = (const float*)d_in[2];
    const float* bproj = (const float*)d_in[3];
    const float* ctok  = (const float*)d_in[4];
    const float* ln1s  = (const float*)d_in[5];
    const float* ln1b  = (const float*)d_in[6];
    const float* Wq    = (const float*)d_in[7];
    const float* Wk    = (const float*)d_in[8];
    const float* Wv    = (const float*)d_in[9];
    const float* Wo    = (const float*)d_in[10];
    const float* bo    = (const float*)d_in[11];
    const float* ln2s  = (const float*)d_in[12];
    const float* ln2b  = (const float*)d_in[13];
    const float* W1    = (const float*)d_in[14];
    const float* b1    = (const float*)d_in[15];
    const float* W2    = (const float*)d_in[16];
    const float* b2    = (const float*)d_in[17];

    char* p = (char*)d_ws;
    unsigned short* bufHb = (unsigned short*)p;           p += (size_t)NTOK*2;      // bf16 h
    float* big = (float*)p;                               p += (size_t)NTOK*2*4;    // 229MB
    unsigned short* qkvb   = (unsigned short*)big;        // bf16 [BSR][768]
    unsigned short* hidb   = (unsigned short*)big;        // bf16 [BSR][1024]
    unsigned short* specb  = (unsigned short*)p;          p += (size_t)BSR*128*2;   // bf16 spec
    unsigned short* bufYb  = (unsigned short*)p;          p += (size_t)NTOK*2;      // bf16 ln out
    unsigned short* framesb= bufYb;                       // bf16 [BSR][256] (pre-layer)
    unsigned short* attb   = bufYb;                       // bf16 att out
    float* ctxb = (float*)p;                              p += (size_t)BB*NHEAD*DH*DH*4;
    float* peb  = (float*)p;                              p += (size_t)TT*EMBD*4;
    unsigned short* twb  = (unsigned short*)p;            p += (size_t)65536*2;
    unsigned short* Wpb  = (unsigned short*)p;            p += (size_t)32768*2;
    unsigned short* wbuf = (unsigned short*)p;            p += (size_t)4*WL*2;
    if(ws_size < (size_t)(p - (char*)d_ws)) return;

    float* out      = (float*)d_out;
    float* o_emb    = out;
    float* o_masked = out + (size_t)NTOK;
    float* o_h      = out + 2*(size_t)NTOK;
    float* o_mask   = out + 3*(size_t)NTOK;

    dim3 blk(256);

    // ---- prep ----
    init_twb<<<256, blk, 0, stream>>>(twb);
    init_pe <<<19,  blk, 0, stream>>>(peb);
    wprep_proj<<<128, blk, 0, stream>>>(Wproj, Wpb);
    wprep_qkv<<<3072, blk, 0, stream>>>(Wq, Wk, Wv, wbuf);
    wprep_wo <<<1024, blk, 0, stream>>>(Wo, wbuf);
    wprep_w1 <<<4096, blk, 0, stream>>>(W1, wbuf);
    wprep_w2 <<<4096, blk, 0, stream>>>(W2, wbuf);

    // ---- front end ----
    frames_bf16<<<4096, blk, 0, stream>>>(x, framesb);
    gemm_dft<<<dim3(2,874), blk, 0, stream>>>(framesb, twb, specb);
    gemm_emb<<<dim3(2,874), blk, 0, stream>>>(specb, Wpb, bproj, ctok, peb, noise,
                                              o_emb, o_masked, o_mask, bufHb);

    // ---- transformer layers ----
    for(int l=0;l<NDEPTH;++l){
        unsigned short* wl   = wbuf + (size_t)l*WL;
        unsigned short* Wqkv = wl;             // [768][256]
        unsigned short* Wot  = wl + 196608;    // [256][256]
        unsigned short* W1t  = wl + 262144;    // [1024][256]
        unsigned short* W2t  = wl + 524288;    // [256][1024]

        ln_bf16<<<BSR/4, blk, 0, stream>>>(bufHb, ln1s + l*EMBD, ln1b + l*EMBD, bufYb);
        gemm_mfma<3><<<dim3(6,874), blk, 0, stream>>>(bufYb, Wqkv, nullptr, qkvb,
                                                      nullptr, BSR, QKVW, EMBD);
        ctx_kernel<<<BB*NHEAD, blk, 0, stream>>>(qkvb, ctxb);
        att_kernel<<<dim3(110, BB), blk, 0, stream>>>(qkvb, ctxb, attb);
        gemm_mfma<1><<<dim3(2,874), blk, 0, stream>>>(attb, Wot, bo + l*EMBD, bufHb,
                                                      bufHb, BSR, EMBD, EMBD);
        ln_bf16<<<BSR/4, blk, 0, stream>>>(bufHb, ln2s + l*EMBD, ln2b + l*EMBD, bufYb);
        gemm_mfma<2><<<dim3(8,874), blk, 0, stream>>>(bufYb, W1t, b1 + l*HID, hidb,
                                                      nullptr, BSR, HID, EMBD);
        if(l == NDEPTH-1)
            gemm_mfma<4><<<dim3(2,874), blk, 0, stream>>>(hidb, W2t, b2 + l*EMBD, o_h,
                                                          bufHb, BSR, EMBD, HID);
        else
            gemm_mfma<1><<<dim3(2,874), blk, 0, stream>>>(hidb, W2t, b2 + l*EMBD, bufHb,
                                                          bufHb, BSR, EMBD, HID);
    }
}